// Round 3
// baseline (1364.895 us; speedup 1.0000x reference)
//
#include <hip/hip_runtime.h>
#include <math.h>

// Problem constants
#define TT 256      // sequence length
#define BB 64       // batch
#define DD 300      // embedding dim
#define KP0 320     // layer-0 K padded to multiple of 32
#define HH 256      // hidden
#define KK 37       // CRF states
#define FH 1024     // 4*H
#define MTOT (TT*BB) // 16384 rows, time-major r = t*64 + b

typedef __attribute__((ext_vector_type(8))) short short8;  // 8 bf16 (4 VGPR) MFMA A/B frag
typedef __attribute__((ext_vector_type(4))) float f32x4;   // MFMA C/D frag

// ---------- bf16 helpers ----------
__device__ __forceinline__ float bf2f(unsigned short u) {
    union { float f; unsigned int i; } v; v.i = ((unsigned int)u) << 16; return v.f;
}
__device__ __forceinline__ unsigned short f2bf(float f) {
    union { float f; unsigned int i; } v; v.f = f;
    unsigned int i = v.i;
    unsigned int r = (i + 0x7FFFu + ((i >> 16) & 1u)) >> 16; // RNE
    return (unsigned short)r;
}
__device__ __forceinline__ float sigm(float x)   { return 1.0f / (1.0f + __expf(-x)); }
__device__ __forceinline__ float tanh_f(float x) { return 2.0f / (1.0f + __expf(-2.0f * x)) - 1.0f; }

// signed byte extract (compiler -> v_bfe_i32)
__device__ __forceinline__ int sb0(int w) { return (w << 24) >> 24; }
__device__ __forceinline__ int sb1(int w) { return (w << 16) >> 24; }
__device__ __forceinline__ int sb2(int w) { return (w <<  8) >> 24; }
__device__ __forceinline__ int sb3(int w) { return  w        >> 24; }

#if defined(__has_builtin)
#if __has_builtin(__builtin_amdgcn_sdot4)
#define HAVE_SDOT4 1
#endif
#endif

// 4x int8 dot product: c += dot(a.bytes, b.bytes)
__device__ __forceinline__ int dot4i8(int a, int b, int c) {
#ifdef HAVE_SDOT4
    return __builtin_amdgcn_sdot4(a, b, c, false);
#else
    return c + sb0(a) * sb0(b) + sb1(a) * sb1(b) + sb2(a) * sb2(b) + sb3(a) * sb3(b);
#endif
}

// accumulate 4 gates for one h-dword against one weight int4
__device__ __forceinline__ void lstm_dot(int hw, int4 wv, int& a0, int& a1, int& a2, int& a3) {
    a0 = dot4i8(hw, wv.x, a0);
    a1 = dot4i8(hw, wv.y, a1);
    a2 = dot4i8(hw, wv.z, a2);
    a3 = dot4i8(hw, wv.w, a3);
}

// permute gate-major col (g*256+unit) -> interleaved (unit*4+g)
__device__ __forceinline__ int perm_col(int nn) { return ((nn & 255) << 2) | (nn >> 8); }

// ---------- prep: per-row quant step S[m][u*4+g] = max_k |Whh[m][(g*256+u)*256+k]| / 127 ----------
__global__ __launch_bounds__(64) void conv_scale(
    const float* __restrict__ w0f, const float* __restrict__ w0b,
    const float* __restrict__ w1f, const float* __restrict__ w1b,
    float* __restrict__ S)   // 4 x 1024
{
    const int m = blockIdx.x >> 10;
    const int r = blockIdx.x & 1023;          // r = g*256 + u
    const float* W = m == 0 ? w0f : m == 1 ? w0b : m == 2 ? w1f : w1b;
    const int t = threadIdx.x;
    float mx = 0.f;
    for (int k = t; k < HH; k += 64) mx = fmaxf(mx, fabsf(W[r * HH + k]));
    #pragma unroll
    for (int s = 32; s > 0; s >>= 1) mx = fmaxf(mx, __shfl_down(mx, s, 64));
    if (t == 0) {
        const int g = r >> 8, u = r & 255;
        S[m * 1024 + u * 4 + g] = fmaxf(mx, 1e-20f) / 127.0f;
    }
}

// ---------- prep: quantize Whh -> WQ int8, word[((kq*16+j)*256+u)*4+g] = 4 k (k0=kq*64+j*4) ----------
__global__ __launch_bounds__(256) void conv_wq(
    const float* __restrict__ w0f, const float* __restrict__ w0b,
    const float* __restrict__ w1f, const float* __restrict__ w1b,
    const float* __restrict__ S, unsigned int* __restrict__ WQ)
{
    const int idx = blockIdx.x * 256 + threadIdx.x;     // 0 .. 4*65536-1
    const int m = idx >> 16;
    const int r = idx & 65535;
    const float* W = m == 0 ? w0f : m == 1 ? w0b : m == 2 ? w1f : w1b;
    const int g  = r & 3;
    const int u  = (r >> 2) & 255;
    const int j  = (r >> 10) & 15;
    const int kq = r >> 14;
    const int k0 = kq * 64 + j * 4;
    const float s = S[m * 1024 + u * 4 + g];
    const float4 wv = *(const float4*)(W + (g * HH + u) * HH + k0);
    int q0 = (int)rintf(wv.x / s), q1 = (int)rintf(wv.y / s);
    int q2 = (int)rintf(wv.z / s), q3 = (int)rintf(wv.w / s);
    q0 = max(-127, min(127, q0)); q1 = max(-127, min(127, q1));
    q2 = max(-127, min(127, q2)); q3 = max(-127, min(127, q3));
    WQ[idx] = (unsigned int)(q0 & 0xff) | ((unsigned int)(q1 & 0xff) << 8) |
              ((unsigned int)(q2 & 0xff) << 16) | ((unsigned int)(q3 & 0xff) << 24);
}

// ---------- prep: Wsbj f32 (37x512) -> bf16 padded (64x512), rows>=37 zero ----------
__global__ __launch_bounds__(256) void conv_wsbj_bf(
    const float* __restrict__ Wsbj, unsigned short* __restrict__ WB)
{
    const int idx = blockIdx.x * 256 + threadIdx.x;   // 0 .. 64*512-1
    if (idx >= 64 * 512) return;
    const int r = idx >> 9, cidx = idx & 511;
    WB[idx] = (r < KK) ? f2bf(Wsbj[r * 512 + cidx]) : (unsigned short)0;
}

// ---------- prep: gather embedding rows -> Abf bf16 [16384][320] (zero-pad k>=300) ----------
__global__ __launch_bounds__(320) void conv_gather(
    const int* __restrict__ text, const float* __restrict__ emb,
    unsigned short* __restrict__ Abf)
{
    const int r = blockIdx.x;
    const int k = threadIdx.x;
    const int t = r >> 6, b = r & 63;
    const int idx = text[b * TT + t];
    Abf[r * KP0 + k] = (k < DD) ? f2bf(emb[(size_t)idx * DD + k]) : (unsigned short)0;
}

// ---------- prep: W f32 (rows x kin) -> bf16 (rows x kout), zero-pad ----------
__global__ __launch_bounds__(256) void conv_w(
    const float* __restrict__ src, unsigned short* __restrict__ dst,
    int kin, int kout, int total)
{
    const int idx = blockIdx.x * 256 + threadIdx.x;
    if (idx >= total) return;
    const int rr = idx / kout, k = idx - rr * kout;
    dst[idx] = (k < kin) ? f2bf(src[rr * kin + k]) : (unsigned short)0;
}

// ---------- MFMA GEMM: out = A(M x lda bf16) @ W(1024 x lda bf16)^T + bias ----------
// 128x128 tile, 256 threads (4 waves, each 64x64 = 4x4 MFMA_16x16x32_bf16).
// Staging via global_load_lds width=16 (linear LDS layout = lane order, no padding).
__global__ __launch_bounds__(256) void gemm_mfma(
    const unsigned short* __restrict__ A,
    const unsigned short* __restrict__ W,
    const float* __restrict__ bias,
    unsigned short* __restrict__ out,
    int lda)
{
    const int bm = blockIdx.x * 128;
    const int bn = blockIdx.y * 128;
    const int tid = threadIdx.x;
    const int lane = tid & 63;
    const int wave = tid >> 6;
    const int wm = (wave & 1) * 64;
    const int wn = (wave >> 1) * 64;

    __shared__ __align__(16) unsigned short As[128 * 32];  // [row][k] 8 KB
    __shared__ __align__(16) unsigned short Bs[128 * 32];  // [wrow][k] 8 KB

    f32x4 acc[4][4] = {};

    const int srow = tid >> 2;          // 0..63
    const int sk = (tid & 3) * 8;       // k element offset (16 B granules)

    const unsigned short* ga0 = A + (size_t)(bm + srow) * lda + sk;
    const unsigned short* ga1 = A + (size_t)(bm + srow + 64) * lda + sk;
    const unsigned short* gb0 = W + (size_t)(bn + srow) * lda + sk;
    const unsigned short* gb1 = W + (size_t)(bn + srow + 64) * lda + sk;

    unsigned short* lA0 = As + wave * 512;
    unsigned short* lA1 = As + 2048 + wave * 512;
    unsigned short* lB0 = Bs + wave * 512;
    unsigned short* lB1 = Bs + 2048 + wave * 512;

    const int kiters = lda >> 5;
    for (int kb = 0; kb < kiters; kb++) {
        const int k0 = kb * 32;
        __builtin_amdgcn_global_load_lds(
            (const __attribute__((address_space(1))) unsigned int*)(ga0 + k0),
            (__attribute__((address_space(3))) unsigned int*)lA0, 16, 0, 0);
        __builtin_amdgcn_global_load_lds(
            (const __attribute__((address_space(1))) unsigned int*)(ga1 + k0),
            (__attribute__((address_space(3))) unsigned int*)lA1, 16, 0, 0);
        __builtin_amdgcn_global_load_lds(
            (const __attribute__((address_space(1))) unsigned int*)(gb0 + k0),
            (__attribute__((address_space(3))) unsigned int*)lB0, 16, 0, 0);
        __builtin_amdgcn_global_load_lds(
            (const __attribute__((address_space(1))) unsigned int*)(gb1 + k0),
            (__attribute__((address_space(3))) unsigned int*)lB1, 16, 0, 0);
        __syncthreads();

        short8 af[4], bfr[4];
        #pragma unroll
        for (int i = 0; i < 4; i++) {
            af[i]  = *(const short8*)&As[(wm + i * 16 + (lane & 15)) * 32 + (lane >> 4) * 8];
            bfr[i] = *(const short8*)&Bs[(wn + i * 16 + (lane & 15)) * 32 + (lane >> 4) * 8];
        }
        #pragma unroll
        for (int i = 0; i < 4; i++)
            #pragma unroll
            for (int j = 0; j < 4; j++)
                acc[i][j] = __builtin_amdgcn_mfma_f32_16x16x32_bf16(af[i], bfr[j], acc[i][j], 0, 0, 0);
        __syncthreads();
    }

    // C/D: col = lane&15, row = (lane>>4)*4 + reg  [measured m89/m91]
    const int cn = lane & 15;
    const int cr = (lane >> 4) * 4;
    #pragma unroll
    for (int j = 0; j < 4; j++) {
        const int n = bn + wn + j * 16 + cn;
        const float bv = bias[n];
        const int pc = perm_col(n);
        #pragma unroll
        for (int i = 0; i < 4; i++) {
            #pragma unroll
            for (int r = 0; r < 4; r++) {
                const int m = bm + wm + i * 16 + cr + r;
                out[(size_t)m * FH + pc] = f2bf(acc[i][j][r] + bv);
            }
        }
    }
}

// ---------- Emission GEMM: em = h1(16384x512 bf16) @ WsbjB(64x512 bf16)^T + bias, f32 out ----------
// 128x64 tile, 256 threads (4 waves, each 64x32 = 4x2 MFMA_16x16x32_bf16).
__global__ __launch_bounds__(256) void gemm_em(
    const unsigned short* __restrict__ A,
    const unsigned short* __restrict__ W,
    const float* __restrict__ bias,
    float* __restrict__ em)
{
    const int bm = blockIdx.x * 128;
    const int tid = threadIdx.x;
    const int lane = tid & 63;
    const int wave = tid >> 6;
    const int wm = (wave & 1) * 64;
    const int wn = (wave >> 1) * 32;

    __shared__ __align__(16) unsigned short As[128 * 32];  // 8 KB
    __shared__ __align__(16) unsigned short Bs[64 * 32];   // 4 KB

    f32x4 acc[4][2] = {};

    const int srow = tid >> 2;          // 0..63
    const int sk = (tid & 3) * 8;

    const unsigned short* ga0 = A + (size_t)(bm + srow) * 512 + sk;
    const unsigned short* ga1 = A + (size_t)(bm + srow + 64) * 512 + sk;
    const unsigned short* gb  = W + (size_t)srow * 512 + sk;

    unsigned short* lA0 = As + wave * 512;
    unsigned short* lA1 = As + 2048 + wave * 512;
    unsigned short* lB  = Bs + wave * 512;

    for (int kb = 0; kb < 16; kb++) {
        const int k0 = kb * 32;
        __builtin_amdgcn_global_load_lds(
            (const __attribute__((address_space(1))) unsigned int*)(ga0 + k0),
            (__attribute__((address_space(3))) unsigned int*)lA0, 16, 0, 0);
        __builtin_amdgcn_global_load_lds(
            (const __attribute__((address_space(1))) unsigned int*)(ga1 + k0),
            (__attribute__((address_space(3))) unsigned int*)lA1, 16, 0, 0);
        __builtin_amdgcn_global_load_lds(
            (const __attribute__((address_space(1))) unsigned int*)(gb + k0),
            (__attribute__((address_space(3))) unsigned int*)lB, 16, 0, 0);
        __syncthreads();

        short8 af[4], bfr[2];
        #pragma unroll
        for (int i = 0; i < 4; i++)
            af[i]  = *(const short8*)&As[(wm + i * 16 + (lane & 15)) * 32 + (lane >> 4) * 8];
        #pragma unroll
        for (int j = 0; j < 2; j++)
            bfr[j] = *(const short8*)&Bs[(wn + j * 16 + (lane & 15)) * 32 + (lane >> 4) * 8];
        #pragma unroll
        for (int i = 0; i < 4; i++)
            #pragma unroll
            for (int j = 0; j < 2; j++)
                acc[i][j] = __builtin_amdgcn_mfma_f32_16x16x32_bf16(af[i], bfr[j], acc[i][j], 0, 0, 0);
        __syncthreads();
    }

    const int cn = lane & 15;
    const int cr = (lane >> 4) * 4;
    #pragma unroll
    for (int j = 0; j < 2; j++) {
        const int n = wn + j * 16 + cn;
        if (n < KK) {
            const float bv = bias[n];
            #pragma unroll
            for (int i = 0; i < 4; i++) {
                #pragma unroll
                for (int r = 0; r < 4; r++) {
                    const int m = bm + wm + i * 16 + cr + r;
                    em[(size_t)m * KK + n] = acc[i][j][r] + bv;
                }
            }
        }
    }
}

// ---------- LSTM recurrence: grid (64 batches, 2 dirs), 256 threads ----------
// R9 REWRITE: full-K per thread. Thread u owns unit u entirely: 64 int4
// (256 B) register-resident weights, 64 sdot4 x4 gates per step, NO split-K
// reduction (red[] and barrier #1 deleted), epilogue on all 256 threads.
// __launch_bounds__(256, 1): 1 wave/EU -> 512-VGPR budget (no spill <=450,
// m08). All weight indices compile-time (full unroll; rule #20).
// zin prefetched ONE STEP AHEAD so L2/L3 latency (~200-900 cyc) stays off
// the critical path. One barrier per step (hq8 write -> next-step read).
__global__ __launch_bounds__(256, 1) void lstm_kernel(
    const unsigned short* __restrict__ zin_f, const unsigned short* __restrict__ zin_b,
    const int* __restrict__ WQf, const int* __restrict__ WQb,
    const float* __restrict__ Sf, const float* __restrict__ Sb,
    unsigned short* __restrict__ h_out)  // (T,B,512) bf16; fwd cols [0:256), bwd [256:512)
{
    const int dir = blockIdx.y;
    const unsigned short* zin = dir ? zin_b : zin_f;
    const int*   WQ = dir ? WQb : WQf;
    const float* S  = dir ? Sb  : Sf;
    const int off = dir ? HH : 0;

    const int b = blockIdx.x;
    const int u = threadIdx.x;          // unit id, 0..255

    __shared__ __align__(16) unsigned char hq8[2][HH];  // int8 h, double-buffered

    // ---- preload this thread's 1 KB of int8 weights into 64 int4 regs ----
    // int4 index j*256+u covers k = (j>>4)*64 + (j&15)*4 .. +3, gates .x..w;
    // matching h dword index = (j>>4)*16 + (j&15) = j  (layout lines up).
    int4 w[64];
    #pragma unroll
    for (int j = 0; j < 64; j++) w[j] = ((const int4*)WQ)[j * 256 + u];

    float4 sc = *(const float4*)(S + 4 * u);
    {
        const float inv127 = 1.0f / 127.0f;
        sc.x *= inv127; sc.y *= inv127; sc.z *= inv127; sc.w *= inv127;
    }
    float c = 0.0f;
    int cur = 0;
    if (u < 128) ((unsigned int*)hq8)[u] = 0u;   // zero both buffers
    __syncthreads();

    // prefetch z for step 0
    ushort4 zv;
    {
        const int tt0 = dir ? (TT - 1) : 0;
        zv = *(const ushort4*)(zin + (tt0 * BB + b) * FH + 4 * u);
    }

    for (int ts = 0; ts < TT; ts++) {
        // prefetch z for the NEXT step (clamped); consumed next iteration,
        // so its vmcnt wait lands after this step's dots+epilogue.
        const int ts_n = (ts + 1 < TT) ? (ts + 1) : ts;
        const int tt_n = dir ? (TT - 1 - ts_n) : ts_n;
        const ushort4 zv_n = *(const ushort4*)(zin + (tt_n * BB + b) * FH + 4 * u);

        // h broadcast: 64 dwords via 16x ds_read_b128, wave-uniform address
        const int4* hv = (const int4*)&hq8[cur][0];
        int a0 = 0, a1 = 0, a2 = 0, a3 = 0;
        #pragma unroll
        for (int jq = 0; jq < 16; jq++) {
            const int4 hw = hv[jq];
            lstm_dot(hw.x, w[4 * jq + 0], a0, a1, a2, a3);
            lstm_dot(hw.y, w[4 * jq + 1], a0, a1, a2, a3);
            lstm_dot(hw.z, w[4 * jq + 2], a0, a1, a2, a3);
            lstm_dot(hw.w, w[4 * jq + 3], a0, a1, a2, a3);
        }

        const int tt = dir ? (TT - 1 - ts) : ts;
        const int row = tt * BB + b;
        const float zi  = (float)a0 * sc.x + bf2f(zv.x);
        const float zf_ = (float)a1 * sc.y + bf2f(zv.y);
        const float zg  = (float)a2 * sc.z + bf2f(zv.z);
        const float zo  = (float)a3 * sc.w + bf2f(zv.w);
        const float cc = sigm(zf_) * c + sigm(zi) * tanh_f(zg);
        c = cc;
        const float hh = sigm(zo) * tanh_f(cc);
        hq8[cur ^ 1][u] = (unsigned char)((int)rintf(hh * 127.0f));
        h_out[row * (2 * HH) + off + u] = f2bf(hh);
        __syncthreads();
        cur ^= 1;
        zv = zv_n;
    }
}

// ---------- CRF: one block (1 wave) per batch ----------
__global__ __launch_bounds__(64) void crf_kernel(
    const int* __restrict__ text, const int* __restrict__ sbj,
    const float* __restrict__ em,
    const float* __restrict__ start_t, const float* __restrict__ end_t,
    const float* __restrict__ trans, float* __restrict__ accum)
{
    const int b = blockIdx.x;
    const int tid = threadIdx.x;
    __shared__ float tr[KK * KK];
    __shared__ float sc[2][KK];
    for (int x = tid; x < KK * KK; x += 64) tr[x] = trans[x];

    int cnt = 0;
    for (int t = tid; t < TT; t += 64) cnt += (text[b * TT + t] != 0) ? 1 : 0;
    #pragma unroll
    for (int s = 32; s > 0; s >>= 1) cnt += __shfl_down(cnt, s, 64);
    const int len = __shfl(cnt, 0, 64);

    __syncthreads();

    float part = 0.f;
    for (int t = tid; t < TT; t += 64) {
        if (t >= 1 && t < len) {
            const int tg = sbj[b * TT + t];
            const int tp = sbj[b * TT + t - 1];
            part += em[(t * BB + b) * KK + tg] + tr[tp * KK + tg];
        }
    }
    #pragma unroll
    for (int s = 32; s > 0; s >>= 1) part += __shfl_down(part, s, 64);

    if (tid < KK) sc[0][tid] = start_t[tid] + em[b * KK + tid];
    __syncthreads();
    int cur = 0;
    for (int t = 1; t < len; t++) {
        float nv = 0.f;
        if (tid < KK) {
            float mx = -1e30f;
            for (int k1 = 0; k1 < KK; k1++)
                mx = fmaxf(mx, sc[cur][k1] + tr[k1 * KK + tid]);
            float s = 0.f;
            for (int k1 = 0; k1 < KK; k1++)
                s += __expf(sc[cur][k1] + tr[k1 * KK + tid] - mx);
            nv = mx + __logf(s) + em[(t * BB + b) * KK + tid];
        }
        if (tid < KK) sc[cur ^ 1][tid] = nv;
        __syncthreads();
        cur ^= 1;
    }

    if (tid == 0) {
        const int tg0 = sbj[b * TT];
        const int tgl = sbj[b * TT + len - 1];
        const float num = start_t[tg0] + em[b * KK + tg0] + part + end_t[tgl];
        float mx = -1e30f;
        for (int k = 0; k < KK; k++) mx = fmaxf(mx, sc[cur][k] + end_t[k]);
        float s = 0.f;
        for (int k = 0; k < KK; k++) s += __expf(sc[cur][k] + end_t[k] - mx);
        const float logZ = mx + __logf(s);
        atomicAdd(&accum[0], num - logZ);
        atomicAdd(&accum[1], (float)len);
    }
}

__global__ void init_kernel(float* __restrict__ accum) {
    if (threadIdx.x < 2) accum[threadIdx.x] = 0.0f;
}
__global__ void final_kernel(const float* __restrict__ accum, float* __restrict__ out) {
    out[0] = -(accum[0] / accum[1]);
}

// ---------- launch ----------
extern "C" void kernel_launch(void* const* d_in, const int* in_sizes, int n_in,
                              void* d_out, int out_size, void* d_ws, size_t ws_size,
                              hipStream_t stream)
{
    (void)in_sizes; (void)n_in; (void)out_size; (void)ws_size;
    const int*   text  = (const int*)d_in[0];
    const int*   sbj   = (const int*)d_in[1];
    const float* emb   = (const float*)d_in[2];
    const float* Wih0f = (const float*)d_in[3];
    const float* Whh0f = (const float*)d_in[4];
    const float* b0f   = (const float*)d_in[5];
    const float* Wih0b = (const float*)d_in[6];
    const float* Whh0b = (const float*)d_in[7];
    const float* b0b   = (const float*)d_in[8];
    const float* Wih1f = (const float*)d_in[9];
    const float* Whh1f = (const float*)d_in[10];
    const float* b1f   = (const float*)d_in[11];
    const float* Wih1b = (const float*)d_in[12];
    const float* Whh1b = (const float*)d_in[13];
    const float* b1b   = (const float*)d_in[14];
    const float* Wsbj  = (const float*)d_in[15];
    const float* bsbj  = (const float*)d_in[16];
    const float* start_t = (const float*)d_in[17];
    const float* end_t   = (const float*)d_in[18];
    const float* trans   = (const float*)d_in[19];

    // workspace map (bytes), max ~102.84 MB. Overlaps (stream-ordered lifetimes):
    //   Wb0f/Wb0b in h0 region (dead before lstm0 writes h0)
    //   Abf, Wb1f/Wb1b in h1 region (dead before lstm1 writes h1)
    //   em reuses zf (dead after lstm1)
    char* ws = (char*)d_ws;
    unsigned short* zf   = (unsigned short*)(ws + 0);           // 32 MiB
    unsigned short* zb   = (unsigned short*)(ws + 33554432);    // 32 MiB
    unsigned short* h0   = (unsigned short*)(ws + 67108864);    // 16 MiB
    unsigned short* h1   = (unsigned short*)(ws + 83886080);    // 16 MiB
    unsigned short* Wb0f = (unsigned short*)(ws + 67108864);    // 1024x320 bf16
    unsigned short* Wb0b = (unsigned short*)(ws + 67764224);
    unsigned short* Abf  = (unsigned short*)(ws + 83886080);    // 16384x320 bf16 (10 MiB)
    unsigned short* Wb1f = (unsigned short*)(ws + 94371840);    // 1024x512 bf16
    unsigned short* Wb1b = (unsigned short*)(ws + 95420416);
    unsigned int*   WQ   = (unsigned int*)(ws + 100663296);     // 4 x 256 KiB int8 weights
    float*          Sq   = (float*)(ws + 101711872);            // 4 x 4 KiB scales
    unsigned short* WsbjB = (unsigned short*)(ws + 102760448);  // 64x512 bf16 (64 KiB)
    float*          acc  = (float*)(ws + 102836224);            // 8 B
    float*           em  = (float*)(ws + 0);                    // 2.4 MiB (over zf)
    float* out = (float*)d_out;

    const int* WQ0f = (const int*)(WQ + 0 * 65536);
    const int* WQ0b = (const int*)(WQ + 1 * 65536);
    const int* WQ1f = (const int*)(WQ + 2 * 65536);
    const int* WQ1b = (const int*)(WQ + 3 * 65536);
    const float* S0f = Sq + 0 * 1024;
    const float* S0b = Sq + 1 * 1024;
    const float* S1f = Sq + 2 * 1024;
    const float* S1b = Sq + 3 * 1024;

    init_kernel<<<1, 64, 0, stream>>>(acc);
    conv_scale<<<dim3(4096), 64, 0, stream>>>(Whh0f, Whh0b, Whh1f, Whh1b, Sq);
    conv_wq<<<dim3(1024), 256, 0, stream>>>(Whh0f, Whh0b, Whh1f, Whh1b, Sq, WQ);
    conv_wsbj_bf<<<dim3(128), 256, 0, stream>>>(Wsbj, WsbjB);
    conv_gather<<<dim3(MTOT), 320, 0, stream>>>(text, emb, Abf);
    conv_w<<<dim3(1280), 256, 0, stream>>>(Wih0f, Wb0f, DD, KP0, 1024 * KP0);
    conv_w<<<dim3(1280), 256, 0, stream>>>(Wih0b, Wb0b, DD, KP0, 1024 * KP0);
    conv_w<<<dim3(2048), 256, 0, stream>>>(Wih1f, Wb1f, 512, 512, 1024 * 512);
    conv_w<<<dim3(2048), 256, 0, stream>>>(Wih1b, Wb1b, 512, 512, 1024 * 512);

    // layer 0 input projection (MFMA)
    gemm_mfma<<<dim3(128, 8), 256, 0, stream>>>(Abf, Wb0f, b0f, zf, KP0);
    gemm_mfma<<<dim3(128, 8), 256, 0, stream>>>(Abf, Wb0b, b0b, zb, KP0);
    lstm_kernel<<<dim3(BB, 2), 256, 0, stream>>>(zf, zb, WQ0f, WQ0b, S0f, S0b, h0);
    // layer 1 input projection (MFMA)
    gemm_mfma<<<dim3(128, 8), 256, 0, stream>>>(h0, Wb1f, b1f, zf, 512);
    gemm_mfma<<<dim3(128, 8), 256, 0, stream>>>(h0, Wb1b, b1b, zb, 512);
    lstm_kernel<<<dim3(BB, 2), 256, 0, stream>>>(zf, zb, WQ1f, WQ1b, S1f, S1b, h1);

    em_gemm_launch:
    gemm_em<<<dim3(128), 256, 0, stream>>>(h1, WsbjB, bsbj, em);
    crf_kernel<<<BB, 64, 0, stream>>>(text, sbj, em, start_t, end_t, trans, acc);
    final_kernel<<<1, 1, 0, stream>>>(acc, out);
}

// Round 5
// 1320.548 us; speedup vs baseline: 1.0336x; 1.0336x over previous
//
#include <hip/hip_runtime.h>
#include <math.h>

// Problem constants
#define TT 256      // sequence length
#define BB 64       // batch
#define DD 300      // embedding dim
#define KP0 320     // layer-0 K padded to multiple of 32
#define HH 256      // hidden
#define KK 37       // CRF states
#define FH 1024     // 4*H
#define MTOT (TT*BB) // 16384 rows, time-major r = t*64 + b

typedef __attribute__((ext_vector_type(8))) short short8;  // 8 bf16 (4 VGPR) MFMA A/B frag
typedef __attribute__((ext_vector_type(4))) float f32x4;   // MFMA C/D frag

// ---------- bf16 helpers ----------
__device__ __forceinline__ float bf2f(unsigned short u) {
    union { float f; unsigned int i; } v; v.i = ((unsigned int)u) << 16; return v.f;
}
__device__ __forceinline__ unsigned short f2bf(float f) {
    union { float f; unsigned int i; } v; v.f = f;
    unsigned int i = v.i;
    unsigned int r = (i + 0x7FFFu + ((i >> 16) & 1u)) >> 16; // RNE
    return (unsigned short)r;
}
__device__ __forceinline__ float sigm(float x)   { return 1.0f / (1.0f + __expf(-x)); }
__device__ __forceinline__ float tanh_f(float x) { return 2.0f / (1.0f + __expf(-2.0f * x)) - 1.0f; }

// signed byte extract (compiler -> v_bfe_i32)
__device__ __forceinline__ int sb0(int w) { return (w << 24) >> 24; }
__device__ __forceinline__ int sb1(int w) { return (w << 16) >> 24; }
__device__ __forceinline__ int sb2(int w) { return (w <<  8) >> 24; }
__device__ __forceinline__ int sb3(int w) { return  w        >> 24; }

#if defined(__has_builtin)
#if __has_builtin(__builtin_amdgcn_sdot4)
#define HAVE_SDOT4 1
#endif
#if __has_builtin(__builtin_amdgcn_mov_dpp)
#define HAVE_DPP 1
#endif
#endif

// 4x int8 dot product: c += dot(a.bytes, b.bytes)
__device__ __forceinline__ int dot4i8(int a, int b, int c) {
#ifdef HAVE_SDOT4
    return __builtin_amdgcn_sdot4(a, b, c, false);
#else
    return c + sb0(a) * sb0(b) + sb1(a) * sb1(b) + sb2(a) * sb2(b) + sb3(a) * sb3(b);
#endif
}

// accumulate 4 gates for one h-dword against one weight int4
__device__ __forceinline__ void lstm_dot(int hw, int4 wv, int& a0, int& a1, int& a2, int& a3) {
    a0 = dot4i8(hw, wv.x, a0);
    a1 = dot4i8(hw, wv.y, a1);
    a2 = dot4i8(hw, wv.z, a2);
    a3 = dot4i8(hw, wv.w, a3);
}

// sum across the 4 lanes of an aligned quad (DPP quad_perm xor butterfly).
// All lanes end with the full sum. 0xB1 = perm[1,0,3,2]; 0x4E = perm[2,3,0,1].
__device__ __forceinline__ int quad_sum(int v) {
#ifdef HAVE_DPP
    v += __builtin_amdgcn_mov_dpp(v, 0xB1, 0xF, 0xF, true);
    v += __builtin_amdgcn_mov_dpp(v, 0x4E, 0xF, 0xF, true);
#else
    v += __shfl_xor(v, 1, 64);
    v += __shfl_xor(v, 2, 64);
#endif
    return v;
}

// permute gate-major col (g*256+unit) -> interleaved (unit*4+g)
__device__ __forceinline__ int perm_col(int nn) { return ((nn & 255) << 2) | (nn >> 8); }

// ---------- prep: per-row quant step S[m][u*4+g] = max_k |Whh[m][(g*256+u)*256+k]| / 127 ----------
__global__ __launch_bounds__(64) void conv_scale(
    const float* __restrict__ w0f, const float* __restrict__ w0b,
    const float* __restrict__ w1f, const float* __restrict__ w1b,
    float* __restrict__ S)   // 4 x 1024
{
    const int m = blockIdx.x >> 10;
    const int r = blockIdx.x & 1023;          // r = g*256 + u
    const float* W = m == 0 ? w0f : m == 1 ? w0b : m == 2 ? w1f : w1b;
    const int t = threadIdx.x;
    float mx = 0.f;
    for (int k = t; k < HH; k += 64) mx = fmaxf(mx, fabsf(W[r * HH + k]));
    #pragma unroll
    for (int s = 32; s > 0; s >>= 1) mx = fmaxf(mx, __shfl_down(mx, s, 64));
    if (t == 0) {
        const int g = r >> 8, u = r & 255;
        S[m * 1024 + u * 4 + g] = fmaxf(mx, 1e-20f) / 127.0f;
    }
}

// ---------- prep: quantize Whh -> WQ int8 ----------
// R4 layout: int4 index = j*1024 + u*4 + kq  (j=0..15 sub-block, kq=0..3 K-quarter),
// word = int4*4 + g. Covers k0 = kq*64 + j*4. Lane-coalesced preload in lstm_kernel:
// thread tid (u=tid>>2, kq=tid&3) reads wp[j*1024 + tid].
__global__ __launch_bounds__(256) void conv_wq(
    const float* __restrict__ w0f, const float* __restrict__ w0b,
    const float* __restrict__ w1f, const float* __restrict__ w1b,
    const float* __restrict__ S, unsigned int* __restrict__ WQ)
{
    const int idx = blockIdx.x * 256 + threadIdx.x;     // 0 .. 4*65536-1
    const int m = idx >> 16;
    const int r = idx & 65535;
    const float* W = m == 0 ? w0f : m == 1 ? w0b : m == 2 ? w1f : w1b;
    const int g  = r & 3;
    const int u  = (r >> 2) & 255;
    const int j  = (r >> 10) & 15;
    const int kq = r >> 14;
    const int k0 = kq * 64 + j * 4;
    const float s = S[m * 1024 + u * 4 + g];
    const float4 wv = *(const float4*)(W + (g * HH + u) * HH + k0);
    int q0 = (int)rintf(wv.x / s), q1 = (int)rintf(wv.y / s);
    int q2 = (int)rintf(wv.z / s), q3 = (int)rintf(wv.w / s);
    q0 = max(-127, min(127, q0)); q1 = max(-127, min(127, q1));
    q2 = max(-127, min(127, q2)); q3 = max(-127, min(127, q3));
    const int out_idx = (m << 16) | (j << 12) | (u << 4) | (kq << 2) | g;
    WQ[out_idx] = (unsigned int)(q0 & 0xff) | ((unsigned int)(q1 & 0xff) << 8) |
                  ((unsigned int)(q2 & 0xff) << 16) | ((unsigned int)(q3 & 0xff) << 24);
}

// ---------- prep: Wsbj f32 (37x512) -> bf16 padded (64x512), rows>=37 zero ----------
__global__ __launch_bounds__(256) void conv_wsbj_bf(
    const float* __restrict__ Wsbj, unsigned short* __restrict__ WB)
{
    const int idx = blockIdx.x * 256 + threadIdx.x;   // 0 .. 64*512-1
    if (idx >= 64 * 512) return;
    const int r = idx >> 9, cidx = idx & 511;
    WB[idx] = (r < KK) ? f2bf(Wsbj[r * 512 + cidx]) : (unsigned short)0;
}

// ---------- prep: gather embedding rows -> Abf bf16 [16384][320] (zero-pad k>=300) ----------
__global__ __launch_bounds__(320) void conv_gather(
    const int* __restrict__ text, const float* __restrict__ emb,
    unsigned short* __restrict__ Abf)
{
    const int r = blockIdx.x;
    const int k = threadIdx.x;
    const int t = r >> 6, b = r & 63;
    const int idx = text[b * TT + t];
    Abf[r * KP0 + k] = (k < DD) ? f2bf(emb[(size_t)idx * DD + k]) : (unsigned short)0;
}

// ---------- prep: W f32 (rows x kin) -> bf16 (rows x kout), zero-pad ----------
__global__ __launch_bounds__(256) void conv_w(
    const float* __restrict__ src, unsigned short* __restrict__ dst,
    int kin, int kout, int total)
{
    const int idx = blockIdx.x * 256 + threadIdx.x;
    if (idx >= total) return;
    const int rr = idx / kout, k = idx - rr * kout;
    dst[idx] = (k < kin) ? f2bf(src[rr * kin + k]) : (unsigned short)0;
}

// ---------- MFMA GEMM: out = A(M x lda bf16) @ W(1024 x lda bf16)^T + bias ----------
// 128x128 tile, 256 threads (4 waves, each 64x64 = 4x4 MFMA_16x16x32_bf16).
// Staging via global_load_lds width=16 (linear LDS layout = lane order, no padding).
__global__ __launch_bounds__(256) void gemm_mfma(
    const unsigned short* __restrict__ A,
    const unsigned short* __restrict__ W,
    const float* __restrict__ bias,
    unsigned short* __restrict__ out,
    int lda)
{
    const int bm = blockIdx.x * 128;
    const int bn = blockIdx.y * 128;
    const int tid = threadIdx.x;
    const int lane = tid & 63;
    const int wave = tid >> 6;
    const int wm = (wave & 1) * 64;
    const int wn = (wave >> 1) * 64;

    __shared__ __align__(16) unsigned short As[128 * 32];  // [row][k] 8 KB
    __shared__ __align__(16) unsigned short Bs[128 * 32];  // [wrow][k] 8 KB

    f32x4 acc[4][4] = {};

    const int srow = tid >> 2;          // 0..63
    const int sk = (tid & 3) * 8;       // k element offset (16 B granules)

    const unsigned short* ga0 = A + (size_t)(bm + srow) * lda + sk;
    const unsigned short* ga1 = A + (size_t)(bm + srow + 64) * lda + sk;
    const unsigned short* gb0 = W + (size_t)(bn + srow) * lda + sk;
    const unsigned short* gb1 = W + (size_t)(bn + srow + 64) * lda + sk;

    unsigned short* lA0 = As + wave * 512;
    unsigned short* lA1 = As + 2048 + wave * 512;
    unsigned short* lB0 = Bs + wave * 512;
    unsigned short* lB1 = Bs + 2048 + wave * 512;

    const int kiters = lda >> 5;
    for (int kb = 0; kb < kiters; kb++) {
        const int k0 = kb * 32;
        __builtin_amdgcn_global_load_lds(
            (const __attribute__((address_space(1))) unsigned int*)(ga0 + k0),
            (__attribute__((address_space(3))) unsigned int*)lA0, 16, 0, 0);
        __builtin_amdgcn_global_load_lds(
            (const __attribute__((address_space(1))) unsigned int*)(ga1 + k0),
            (__attribute__((address_space(3))) unsigned int*)lA1, 16, 0, 0);
        __builtin_amdgcn_global_load_lds(
            (const __attribute__((address_space(1))) unsigned int*)(gb0 + k0),
            (__attribute__((address_space(3))) unsigned int*)lB0, 16, 0, 0);
        __builtin_amdgcn_global_load_lds(
            (const __attribute__((address_space(1))) unsigned int*)(gb1 + k0),
            (__attribute__((address_space(3))) unsigned int*)lB1, 16, 0, 0);
        __syncthreads();

        short8 af[4], bfr[4];
        #pragma unroll
        for (int i = 0; i < 4; i++) {
            af[i]  = *(const short8*)&As[(wm + i * 16 + (lane & 15)) * 32 + (lane >> 4) * 8];
            bfr[i] = *(const short8*)&Bs[(wn + i * 16 + (lane & 15)) * 32 + (lane >> 4) * 8];
        }
        #pragma unroll
        for (int i = 0; i < 4; i++)
            #pragma unroll
            for (int j = 0; j < 4; j++)
                acc[i][j] = __builtin_amdgcn_mfma_f32_16x16x32_bf16(af[i], bfr[j], acc[i][j], 0, 0, 0);
        __syncthreads();
    }

    // C/D: col = lane&15, row = (lane>>4)*4 + reg  [measured m89/m91]
    const int cn = lane & 15;
    const int cr = (lane >> 4) * 4;
    #pragma unroll
    for (int j = 0; j < 4; j++) {
        const int n = bn + wn + j * 16 + cn;
        const float bv = bias[n];
        const int pc = perm_col(n);
        #pragma unroll
        for (int i = 0; i < 4; i++) {
            #pragma unroll
            for (int r = 0; r < 4; r++) {
                const int m = bm + wm + i * 16 + cr + r;
                out[(size_t)m * FH + pc] = f2bf(acc[i][j][r] + bv);
            }
        }
    }
}

// ---------- Emission GEMM: em = h1(16384x512 bf16) @ WsbjB(64x512 bf16)^T + bias, f32 out ----------
// 128x64 tile, 256 threads (4 waves, each 64x32 = 4x2 MFMA_16x16x32_bf16).
__global__ __launch_bounds__(256) void gemm_em(
    const unsigned short* __restrict__ A,
    const unsigned short* __restrict__ W,
    const float* __restrict__ bias,
    float* __restrict__ em)
{
    const int bm = blockIdx.x * 128;
    const int tid = threadIdx.x;
    const int lane = tid & 63;
    const int wave = tid >> 6;
    const int wm = (wave & 1) * 64;
    const int wn = (wave >> 1) * 32;

    __shared__ __align__(16) unsigned short As[128 * 32];  // 8 KB
    __shared__ __align__(16) unsigned short Bs[64 * 32];   // 4 KB

    f32x4 acc[4][2] = {};

    const int srow = tid >> 2;          // 0..63
    const int sk = (tid & 3) * 8;

    const unsigned short* ga0 = A + (size_t)(bm + srow) * 512 + sk;
    const unsigned short* ga1 = A + (size_t)(bm + srow + 64) * 512 + sk;
    const unsigned short* gb  = W + (size_t)srow * 512 + sk;

    unsigned short* lA0 = As + wave * 512;
    unsigned short* lA1 = As + 2048 + wave * 512;
    unsigned short* lB  = Bs + wave * 512;

    for (int kb = 0; kb < 16; kb++) {
        const int k0 = kb * 32;
        __builtin_amdgcn_global_load_lds(
            (const __attribute__((address_space(1))) unsigned int*)(ga0 + k0),
            (__attribute__((address_space(3))) unsigned int*)lA0, 16, 0, 0);
        __builtin_amdgcn_global_load_lds(
            (const __attribute__((address_space(1))) unsigned int*)(ga1 + k0),
            (__attribute__((address_space(3))) unsigned int*)lA1, 16, 0, 0);
        __builtin_amdgcn_global_load_lds(
            (const __attribute__((address_space(1))) unsigned int*)(gb + k0),
            (__attribute__((address_space(3))) unsigned int*)lB, 16, 0, 0);
        __syncthreads();

        short8 af[4], bfr[2];
        #pragma unroll
        for (int i = 0; i < 4; i++)
            af[i]  = *(const short8*)&As[(wm + i * 16 + (lane & 15)) * 32 + (lane >> 4) * 8];
        #pragma unroll
        for (int j = 0; j < 2; j++)
            bfr[j] = *(const short8*)&Bs[(wn + j * 16 + (lane & 15)) * 32 + (lane >> 4) * 8];
        #pragma unroll
        for (int i = 0; i < 4; i++)
            #pragma unroll
            for (int j = 0; j < 2; j++)
                acc[i][j] = __builtin_amdgcn_mfma_f32_16x16x32_bf16(af[i], bfr[j], acc[i][j], 0, 0, 0);
        __syncthreads();
    }

    const int cn = lane & 15;
    const int cr = (lane >> 4) * 4;
    #pragma unroll
    for (int j = 0; j < 2; j++) {
        const int n = wn + j * 16 + cn;
        if (n < KK) {
            const float bv = bias[n];
            #pragma unroll
            for (int i = 0; i < 4; i++) {
                #pragma unroll
                for (int r = 0; r < 4; r++) {
                    const int m = bm + wm + i * 16 + cr + r;
                    em[(size_t)m * KK + n] = acc[i][j][r] + bv;
                }
            }
        }
    }
}

// ---------- LSTM recurrence: grid (64 batches, 2 dirs), 1024 threads ----------
// R10: intra-wave K-split. tid -> u = tid>>2 (unit), kq = tid&3 (K quarter).
// Each thread: 16 named int4 weights (64 VGPR, same budget as the proven R8
// version, VGPR_Count 52), K-range kq*64..+64. The 4 partials of a unit sit
// in an aligned lane QUAD -> cross-kq reduce is 2 DPP quad_perm xor steps
// (VALU, ~30 cyc) replacing the red[] LDS roundtrip + extra barrier (~400 cyc).
// Epilogue computed redundantly by all 4 lanes (deterministic); lane kq==0
// writes. One barrier per step. LDS = 512 B (hq8 only).
// LESSON R9: >=64 int4/thread cannot fit the 256-VGPR addressable file ->
// spill (VGPR_Count 152, 417us). Keep per-thread arrays <= 16 int4.
__global__ __launch_bounds__(1024, 4) void lstm_kernel(
    const unsigned short* __restrict__ zin_f, const unsigned short* __restrict__ zin_b,
    const int* __restrict__ WQf, const int* __restrict__ WQb,
    const float* __restrict__ Sf, const float* __restrict__ Sb,
    unsigned short* __restrict__ h_out)  // (T,B,512) bf16; fwd cols [0:256), bwd [256:512)
{
    const int dir = blockIdx.y;
    const unsigned short* zin = dir ? zin_b : zin_f;
    const int*   WQ = dir ? WQb : WQf;
    const float* S  = dir ? Sb  : Sf;
    const int off = dir ? HH : 0;

    const int b = blockIdx.x;
    const int tid = threadIdx.x;
    const int u  = tid >> 2;            // unit id, 0..255
    const int kq = tid & 3;             // K quarter (lane quad position)

    __shared__ __align__(16) unsigned char hq8[2][HH];  // int8 h, double-buffered

    // ---- preload 16 named int4 weights, lane-coalesced: idx = j*1024 + tid ----
    // w_j covers k = kq*64 + j*4 .. +3 for gates x..w  <-> h dword kq*16 + j.
    const int4* wp = (const int4*)WQ + tid;
    const int4 w0  = wp[ 0 * 1024], w1  = wp[ 1 * 1024], w2  = wp[ 2 * 1024], w3  = wp[ 3 * 1024];
    const int4 w4  = wp[ 4 * 1024], w5  = wp[ 5 * 1024], w6  = wp[ 6 * 1024], w7  = wp[ 7 * 1024];
    const int4 w8  = wp[ 8 * 1024], w9  = wp[ 9 * 1024], w10 = wp[10 * 1024], w11 = wp[11 * 1024];
    const int4 w12 = wp[12 * 1024], w13 = wp[13 * 1024], w14 = wp[14 * 1024], w15 = wp[15 * 1024];

    float4 sc = *(const float4*)(S + 4 * u);   // same address across the quad (broadcast)
    {
        const float inv127 = 1.0f / 127.0f;
        sc.x *= inv127; sc.y *= inv127; sc.z *= inv127; sc.w *= inv127;
    }
    float c = 0.0f;
    int cur = 0;
    if (tid < 128) ((unsigned int*)hq8)[tid] = 0u;   // zero both buffers
    __syncthreads();

    for (int ts = 0; ts < TT; ts++) {
        const int tt = dir ? (TT - 1 - ts) : ts;
        const int row = tt * BB + b;

        // z load issued early; same address across the quad; consumed post-dots
        const ushort4 zv = *(const ushort4*)(zin + row * FH + 4 * u);

        // h quarter for this lane: 64 bytes at hq8[cur][kq*64], 4x ds_read_b128.
        // 4 distinct addresses/wave -> <=2-way bank alias (free, m136).
        const int4* hv = (const int4*)&hq8[cur][kq * 64];
        const int4 hA = hv[0], hB = hv[1], hC = hv[2], hD = hv[3];

        int a0 = 0, a1 = 0, a2 = 0, a3 = 0;
        lstm_dot(hA.x, w0,  a0, a1, a2, a3);
        lstm_dot(hA.y, w1,  a0, a1, a2, a3);
        lstm_dot(hA.z, w2,  a0, a1, a2, a3);
        lstm_dot(hA.w, w3,  a0, a1, a2, a3);
        lstm_dot(hB.x, w4,  a0, a1, a2, a3);
        lstm_dot(hB.y, w5,  a0, a1, a2, a3);
        lstm_dot(hB.z, w6,  a0, a1, a2, a3);
        lstm_dot(hB.w, w7,  a0, a1, a2, a3);
        lstm_dot(hC.x, w8,  a0, a1, a2, a3);
        lstm_dot(hC.y, w9,  a0, a1, a2, a3);
        lstm_dot(hC.z, w10, a0, a1, a2, a3);
        lstm_dot(hC.w, w11, a0, a1, a2, a3);
        lstm_dot(hD.x, w12, a0, a1, a2, a3);
        lstm_dot(hD.y, w13, a0, a1, a2, a3);
        lstm_dot(hD.z, w14, a0, a1, a2, a3);
        lstm_dot(hD.w, w15, a0, a1, a2, a3);

        // cross-quarter reduce inside the lane quad (all lanes get full sums)
        a0 = quad_sum(a0); a1 = quad_sum(a1);
        a2 = quad_sum(a2); a3 = quad_sum(a3);

        // epilogue: redundant across the quad (identical fp ops -> identical c)
        const float zi  = (float)a0 * sc.x + bf2f(zv.x);
        const float zf_ = (float)a1 * sc.y + bf2f(zv.y);
        const float zg  = (float)a2 * sc.z + bf2f(zv.z);
        const float zo  = (float)a3 * sc.w + bf2f(zv.w);
        const float cc = sigm(zf_) * c + sigm(zi) * tanh_f(zg);
        c = cc;
        const float hh = sigm(zo) * tanh_f(cc);
        if (kq == 0) {
            hq8[cur ^ 1][u] = (unsigned char)((int)rintf(hh * 127.0f));
            h_out[row * (2 * HH) + off + u] = f2bf(hh);
        }
        __syncthreads();
        cur ^= 1;
    }
}

// ---------- CRF: one block (1 wave) per batch ----------
__global__ __launch_bounds__(64) void crf_kernel(
    const int* __restrict__ text, const int* __restrict__ sbj,
    const float* __restrict__ em,
    const float* __restrict__ start_t, const float* __restrict__ end_t,
    const float* __restrict__ trans, float* __restrict__ accum)
{
    const int b = blockIdx.x;
    const int tid = threadIdx.x;
    __shared__ float tr[KK * KK];
    __shared__ float sc[2][KK];
    for (int x = tid; x < KK * KK; x += 64) tr[x] = trans[x];

    int cnt = 0;
    for (int t = tid; t < TT; t += 64) cnt += (text[b * TT + t] != 0) ? 1 : 0;
    #pragma unroll
    for (int s = 32; s > 0; s >>= 1) cnt += __shfl_down(cnt, s, 64);
    const int len = __shfl(cnt, 0, 64);

    __syncthreads();

    float part = 0.f;
    for (int t = tid; t < TT; t += 64) {
        if (t >= 1 && t < len) {
            const int tg = sbj[b * TT + t];
            const int tp = sbj[b * TT + t - 1];
            part += em[(t * BB + b) * KK + tg] + tr[tp * KK + tg];
        }
    }
    #pragma unroll
    for (int s = 32; s > 0; s >>= 1) part += __shfl_down(part, s, 64);

    if (tid < KK) sc[0][tid] = start_t[tid] + em[b * KK + tid];
    __syncthreads();
    int cur = 0;
    for (int t = 1; t < len; t++) {
        float nv = 0.f;
        if (tid < KK) {
            float mx = -1e30f;
            for (int k1 = 0; k1 < KK; k1++)
                mx = fmaxf(mx, sc[cur][k1] + tr[k1 * KK + tid]);
            float s = 0.f;
            for (int k1 = 0; k1 < KK; k1++)
                s += __expf(sc[cur][k1] + tr[k1 * KK + tid] - mx);
            nv = mx + __logf(s) + em[(t * BB + b) * KK + tid];
        }
        if (tid < KK) sc[cur ^ 1][tid] = nv;
        __syncthreads();
        cur ^= 1;
    }

    if (tid == 0) {
        const int tg0 = sbj[b * TT];
        const int tgl = sbj[b * TT + len - 1];
        const float num = start_t[tg0] + em[b * KK + tg0] + part + end_t[tgl];
        float mx = -1e30f;
        for (int k = 0; k < KK; k++) mx = fmaxf(mx, sc[cur][k] + end_t[k]);
        float s = 0.f;
        for (int k = 0; k < KK; k++) s += __expf(sc[cur][k] + end_t[k] - mx);
        const float logZ = mx + __logf(s);
        atomicAdd(&accum[0], num - logZ);
        atomicAdd(&accum[1], (float)len);
    }
}

__global__ void init_kernel(float* __restrict__ accum) {
    if (threadIdx.x < 2) accum[threadIdx.x] = 0.0f;
}
__global__ void final_kernel(const float* __restrict__ accum, float* __restrict__ out) {
    out[0] = -(accum[0] / accum[1]);
}

// ---------- launch ----------
extern "C" void kernel_launch(void* const* d_in, const int* in_sizes, int n_in,
                              void* d_out, int out_size, void* d_ws, size_t ws_size,
                              hipStream_t stream)
{
    (void)in_sizes; (void)n_in; (void)out_size; (void)ws_size;
    const int*   text  = (const int*)d_in[0];
    const int*   sbj   = (const int*)d_in[1];
    const float* emb   = (const float*)d_in[2];
    const float* Wih0f = (const float*)d_in[3];
    const float* Whh0f = (const float*)d_in[4];
    const float* b0f   = (const float*)d_in[5];
    const float* Wih0b = (const float*)d_in[6];
    const float* Whh0b = (const float*)d_in[7];
    const float* b0b   = (const float*)d_in[8];
    const float* Wih1f = (const float*)d_in[9];
    const float* Whh1f = (const float*)d_in[10];
    const float* b1f   = (const float*)d_in[11];
    const float* Wih1b = (const float*)d_in[12];
    const float* Whh1b = (const float*)d_in[13];
    const float* b1b   = (const float*)d_in[14];
    const float* Wsbj  = (const float*)d_in[15];
    const float* bsbj  = (const float*)d_in[16];
    const float* start_t = (const float*)d_in[17];
    const float* end_t   = (const float*)d_in[18];
    const float* trans   = (const float*)d_in[19];

    // workspace map (bytes), max ~102.84 MB. Overlaps (stream-ordered lifetimes):
    //   Wb0f/Wb0b in h0 region (dead before lstm0 writes h0)
    //   Abf, Wb1f/Wb1b in h1 region (dead before lstm1 writes h1)
    //   em reuses zf (dead after lstm1)
    char* ws = (char*)d_ws;
    unsigned short* zf   = (unsigned short*)(ws + 0);           // 32 MiB
    unsigned short* zb   = (unsigned short*)(ws + 33554432);    // 32 MiB
    unsigned short* h0   = (unsigned short*)(ws + 67108864);    // 16 MiB
    unsigned short* h1   = (unsigned short*)(ws + 83886080);    // 16 MiB
    unsigned short* Wb0f = (unsigned short*)(ws + 67108864);    // 1024x320 bf16
    unsigned short* Wb0b = (unsigned short*)(ws + 67764224);
    unsigned short* Abf  = (unsigned short*)(ws + 83886080);    // 16384x320 bf16 (10 MiB)
    unsigned short* Wb1f = (unsigned short*)(ws + 94371840);    // 1024x512 bf16
    unsigned short* Wb1b = (unsigned short*)(ws + 95420416);
    unsigned int*   WQ   = (unsigned int*)(ws + 100663296);     // 4 x 256 KiB int8 weights
    float*          Sq   = (float*)(ws + 101711872);            // 4 x 4 KiB scales
    unsigned short* WsbjB = (unsigned short*)(ws + 102760448);  // 64x512 bf16 (64 KiB)
    float*          acc  = (float*)(ws + 102836224);            // 8 B
    float*           em  = (float*)(ws + 0);                    // 2.4 MiB (over zf)
    float* out = (float*)d_out;

    const int* WQ0f = (const int*)(WQ + 0 * 65536);
    const int* WQ0b = (const int*)(WQ + 1 * 65536);
    const int* WQ1f = (const int*)(WQ + 2 * 65536);
    const int* WQ1b = (const int*)(WQ + 3 * 65536);
    const float* S0f = Sq + 0 * 1024;
    const float* S0b = Sq + 1 * 1024;
    const float* S1f = Sq + 2 * 1024;
    const float* S1b = Sq + 3 * 1024;

    init_kernel<<<1, 64, 0, stream>>>(acc);
    conv_scale<<<dim3(4096), 64, 0, stream>>>(Whh0f, Whh0b, Whh1f, Whh1b, Sq);
    conv_wq<<<dim3(1024), 256, 0, stream>>>(Whh0f, Whh0b, Whh1f, Whh1b, Sq, WQ);
    conv_wsbj_bf<<<dim3(128), 256, 0, stream>>>(Wsbj, WsbjB);
    conv_gather<<<dim3(MTOT), 320, 0, stream>>>(text, emb, Abf);
    conv_w<<<dim3(1280), 256, 0, stream>>>(Wih0f, Wb0f, DD, KP0, 1024 * KP0);
    conv_w<<<dim3(1280), 256, 0, stream>>>(Wih0b, Wb0b, DD, KP0, 1024 * KP0);
    conv_w<<<dim3(2048), 256, 0, stream>>>(Wih1f, Wb1f, 512, 512, 1024 * 512);
    conv_w<<<dim3(2048), 256, 0, stream>>>(Wih1b, Wb1b, 512, 512, 1024 * 512);

    // layer 0 input projection (MFMA)
    gemm_mfma<<<dim3(128, 8), 256, 0, stream>>>(Abf, Wb0f, b0f, zf, KP0);
    gemm_mfma<<<dim3(128, 8), 256, 0, stream>>>(Abf, Wb0b, b0b, zb, KP0);
    lstm_kernel<<<dim3(BB, 2), 1024, 0, stream>>>(zf, zb, WQ0f, WQ0b, S0f, S0b, h0);
    // layer 1 input projection (MFMA)
    gemm_mfma<<<dim3(128, 8), 256, 0, stream>>>(h0, Wb1f, b1f, zf, 512);
    gemm_mfma<<<dim3(128, 8), 256, 0, stream>>>(h0, Wb1b, b1b, zb, 512);
    lstm_kernel<<<dim3(BB, 2), 1024, 0, stream>>>(zf, zb, WQ1f, WQ1b, S1f, S1b, h1);

    gemm_em<<<dim3(128), 256, 0, stream>>>(h1, WsbjB, bsbj, em);
    crf_kernel<<<BB, 64, 0, stream>>>(text, sbj, em, start_t, end_t, trans, acc);
    final_kernel<<<1, 1, 0, stream>>>(acc, out);
}

// Round 6
// 1017.968 us; speedup vs baseline: 1.3408x; 1.2972x over previous
//
#include <hip/hip_runtime.h>
#include <math.h>

// Problem constants
#define TT 256      // sequence length
#define BB 64       // batch
#define DD 300      // embedding dim
#define KP0 320     // layer-0 K padded to multiple of 32
#define HH 256      // hidden
#define KK 37       // CRF states
#define FH 1024     // 4*H
#define MTOT (TT*BB) // 16384 rows, time-major r = t*64 + b

typedef __attribute__((ext_vector_type(8))) short short8;  // 8 bf16 (4 VGPR) MFMA A/B frag
typedef __attribute__((ext_vector_type(4))) float f32x4;   // MFMA C/D frag

// ---------- bf16 helpers ----------
__device__ __forceinline__ float bf2f(unsigned short u) {
    union { float f; unsigned int i; } v; v.i = ((unsigned int)u) << 16; return v.f;
}
__device__ __forceinline__ unsigned short f2bf(float f) {
    union { float f; unsigned int i; } v; v.f = f;
    unsigned int i = v.i;
    unsigned int r = (i + 0x7FFFu + ((i >> 16) & 1u)) >> 16; // RNE
    return (unsigned short)r;
}
__device__ __forceinline__ float sigm(float x)   { return 1.0f / (1.0f + __expf(-x)); }
__device__ __forceinline__ float tanh_f(float x) { return 2.0f / (1.0f + __expf(-2.0f * x)) - 1.0f; }

// signed byte extract (compiler -> v_bfe_i32)
__device__ __forceinline__ int sb0(int w) { return (w << 24) >> 24; }
__device__ __forceinline__ int sb1(int w) { return (w << 16) >> 24; }
__device__ __forceinline__ int sb2(int w) { return (w <<  8) >> 24; }
__device__ __forceinline__ int sb3(int w) { return  w        >> 24; }

#if defined(__has_builtin)
#if __has_builtin(__builtin_amdgcn_sdot4)
#define HAVE_SDOT4 1
#endif
#endif

// 4x int8 dot product: c += dot(a.bytes, b.bytes)
__device__ __forceinline__ int dot4i8(int a, int b, int c) {
#ifdef HAVE_SDOT4
    return __builtin_amdgcn_sdot4(a, b, c, false);
#else
    return c + sb0(a) * sb0(b) + sb1(a) * sb1(b) + sb2(a) * sb2(b) + sb3(a) * sb3(b);
#endif
}

// accumulate 4 gates for one h-dword against one weight int4
__device__ __forceinline__ void lstm_dot(int hw, int4 wv, int& a0, int& a1, int& a2, int& a3) {
    a0 = dot4i8(hw, wv.x, a0);
    a1 = dot4i8(hw, wv.y, a1);
    a2 = dot4i8(hw, wv.z, a2);
    a3 = dot4i8(hw, wv.w, a3);
}

// permute gate-major col (g*256+unit) -> interleaved (unit*4+g)
__device__ __forceinline__ int perm_col(int nn) { return ((nn & 255) << 2) | (nn >> 8); }

// ---------- prep: per-row quant step S[m][u*4+g] = max_k |Whh[m][(g*256+u)*256+k]| / 127 ----------
__global__ __launch_bounds__(64) void conv_scale(
    const float* __restrict__ w0f, const float* __restrict__ w0b,
    const float* __restrict__ w1f, const float* __restrict__ w1b,
    float* __restrict__ S)   // 4 x 1024
{
    const int m = blockIdx.x >> 10;
    const int r = blockIdx.x & 1023;          // r = g*256 + u
    const float* W = m == 0 ? w0f : m == 1 ? w0b : m == 2 ? w1f : w1b;
    const int t = threadIdx.x;
    float mx = 0.f;
    for (int k = t; k < HH; k += 64) mx = fmaxf(mx, fabsf(W[r * HH + k]));
    #pragma unroll
    for (int s = 32; s > 0; s >>= 1) mx = fmaxf(mx, __shfl_down(mx, s, 64));
    if (t == 0) {
        const int g = r >> 8, u = r & 255;
        S[m * 1024 + u * 4 + g] = fmaxf(mx, 1e-20f) / 127.0f;
    }
}

// ---------- prep: quantize Whh -> WQ int8, word[((kq*16+j)*256+u)*4+g] = 4 k (k0=kq*64+j*4) ----------
// (R2-proven layout; lstm reads wp = WQ_int4 + kq*16*256 + u, stride j*256.)
__global__ __launch_bounds__(256) void conv_wq(
    const float* __restrict__ w0f, const float* __restrict__ w0b,
    const float* __restrict__ w1f, const float* __restrict__ w1b,
    const float* __restrict__ S, unsigned int* __restrict__ WQ)
{
    const int idx = blockIdx.x * 256 + threadIdx.x;     // 0 .. 4*65536-1
    const int m = idx >> 16;
    const int r = idx & 65535;
    const float* W = m == 0 ? w0f : m == 1 ? w0b : m == 2 ? w1f : w1b;
    const int g  = r & 3;
    const int u  = (r >> 2) & 255;
    const int j  = (r >> 10) & 15;
    const int kq = r >> 14;
    const int k0 = kq * 64 + j * 4;
    const float s = S[m * 1024 + u * 4 + g];
    const float4 wv = *(const float4*)(W + (g * HH + u) * HH + k0);
    int q0 = (int)rintf(wv.x / s), q1 = (int)rintf(wv.y / s);
    int q2 = (int)rintf(wv.z / s), q3 = (int)rintf(wv.w / s);
    q0 = max(-127, min(127, q0)); q1 = max(-127, min(127, q1));
    q2 = max(-127, min(127, q2)); q3 = max(-127, min(127, q3));
    WQ[idx] = (unsigned int)(q0 & 0xff) | ((unsigned int)(q1 & 0xff) << 8) |
              ((unsigned int)(q2 & 0xff) << 16) | ((unsigned int)(q3 & 0xff) << 24);
}

// ---------- prep: Wsbj f32 (37x512) -> bf16 padded (64x512), rows>=37 zero ----------
__global__ __launch_bounds__(256) void conv_wsbj_bf(
    const float* __restrict__ Wsbj, unsigned short* __restrict__ WB)
{
    const int idx = blockIdx.x * 256 + threadIdx.x;   // 0 .. 64*512-1
    if (idx >= 64 * 512) return;
    const int r = idx >> 9, cidx = idx & 511;
    WB[idx] = (r < KK) ? f2bf(Wsbj[r * 512 + cidx]) : (unsigned short)0;
}

// ---------- prep: gather embedding rows -> Abf bf16 [16384][320] (zero-pad k>=300) ----------
__global__ __launch_bounds__(320) void conv_gather(
    const int* __restrict__ text, const float* __restrict__ emb,
    unsigned short* __restrict__ Abf)
{
    const int r = blockIdx.x;
    const int k = threadIdx.x;
    const int t = r >> 6, b = r & 63;
    const int idx = text[b * TT + t];
    Abf[r * KP0 + k] = (k < DD) ? f2bf(emb[(size_t)idx * DD + k]) : (unsigned short)0;
}

// ---------- prep: W f32 (rows x kin) -> bf16 (rows x kout), zero-pad ----------
__global__ __launch_bounds__(256) void conv_w(
    const float* __restrict__ src, unsigned short* __restrict__ dst,
    int kin, int kout, int total)
{
    const int idx = blockIdx.x * 256 + threadIdx.x;
    if (idx >= total) return;
    const int rr = idx / kout, k = idx - rr * kout;
    dst[idx] = (k < kin) ? f2bf(src[rr * kin + k]) : (unsigned short)0;
}

// ---------- MFMA GEMM (f+b merged on blockIdx.z): out_z = A @ W_z^T + bias_z ----------
// 128x128 tile, 256 threads (4 waves, each 64x64 = 4x4 MFMA_16x16x32_bf16).
// Staging via global_load_lds width=16 (linear LDS layout = lane order, no padding).
__global__ __launch_bounds__(256) void gemm_mfma2(
    const unsigned short* __restrict__ A,
    const unsigned short* __restrict__ Wf,
    const unsigned short* __restrict__ Wb,
    const float* __restrict__ biasf,
    const float* __restrict__ biasb,
    unsigned short* __restrict__ outf,
    unsigned short* __restrict__ outb,
    int lda)
{
    const unsigned short* W = blockIdx.z ? Wb : Wf;
    const float* bias        = blockIdx.z ? biasb : biasf;
    unsigned short* out      = blockIdx.z ? outb : outf;

    const int bm = blockIdx.x * 128;
    const int bn = blockIdx.y * 128;
    const int tid = threadIdx.x;
    const int lane = tid & 63;
    const int wave = tid >> 6;
    const int wm = (wave & 1) * 64;
    const int wn = (wave >> 1) * 64;

    __shared__ __align__(16) unsigned short As[128 * 32];  // [row][k] 8 KB
    __shared__ __align__(16) unsigned short Bs[128 * 32];  // [wrow][k] 8 KB

    f32x4 acc[4][4] = {};

    const int srow = tid >> 2;          // 0..63
    const int sk = (tid & 3) * 8;       // k element offset (16 B granules)

    const unsigned short* ga0 = A + (size_t)(bm + srow) * lda + sk;
    const unsigned short* ga1 = A + (size_t)(bm + srow + 64) * lda + sk;
    const unsigned short* gb0 = W + (size_t)(bn + srow) * lda + sk;
    const unsigned short* gb1 = W + (size_t)(bn + srow + 64) * lda + sk;

    unsigned short* lA0 = As + wave * 512;
    unsigned short* lA1 = As + 2048 + wave * 512;
    unsigned short* lB0 = Bs + wave * 512;
    unsigned short* lB1 = Bs + 2048 + wave * 512;

    const int kiters = lda >> 5;
    for (int kb = 0; kb < kiters; kb++) {
        const int k0 = kb * 32;
        __builtin_amdgcn_global_load_lds(
            (const __attribute__((address_space(1))) unsigned int*)(ga0 + k0),
            (__attribute__((address_space(3))) unsigned int*)lA0, 16, 0, 0);
        __builtin_amdgcn_global_load_lds(
            (const __attribute__((address_space(1))) unsigned int*)(ga1 + k0),
            (__attribute__((address_space(3))) unsigned int*)lA1, 16, 0, 0);
        __builtin_amdgcn_global_load_lds(
            (const __attribute__((address_space(1))) unsigned int*)(gb0 + k0),
            (__attribute__((address_space(3))) unsigned int*)lB0, 16, 0, 0);
        __builtin_amdgcn_global_load_lds(
            (const __attribute__((address_space(1))) unsigned int*)(gb1 + k0),
            (__attribute__((address_space(3))) unsigned int*)lB1, 16, 0, 0);
        __syncthreads();

        short8 af[4], bfr[4];
        #pragma unroll
        for (int i = 0; i < 4; i++) {
            af[i]  = *(const short8*)&As[(wm + i * 16 + (lane & 15)) * 32 + (lane >> 4) * 8];
            bfr[i] = *(const short8*)&Bs[(wn + i * 16 + (lane & 15)) * 32 + (lane >> 4) * 8];
        }
        #pragma unroll
        for (int i = 0; i < 4; i++)
            #pragma unroll
            for (int j = 0; j < 4; j++)
                acc[i][j] = __builtin_amdgcn_mfma_f32_16x16x32_bf16(af[i], bfr[j], acc[i][j], 0, 0, 0);
        __syncthreads();
    }

    // C/D: col = lane&15, row = (lane>>4)*4 + reg  [measured m89/m91]
    const int cn = lane & 15;
    const int cr = (lane >> 4) * 4;
    #pragma unroll
    for (int j = 0; j < 4; j++) {
        const int n = bn + wn + j * 16 + cn;
        const float bv = bias[n];
        const int pc = perm_col(n);
        #pragma unroll
        for (int i = 0; i < 4; i++) {
            #pragma unroll
            for (int r = 0; r < 4; r++) {
                const int m = bm + wm + i * 16 + cr + r;
                out[(size_t)m * FH + pc] = f2bf(acc[i][j][r] + bv);
            }
        }
    }
}

// ---------- Emission GEMM: em = h1(16384x512 bf16) @ WsbjB(64x512 bf16)^T + bias, f32 out ----------
// 128x64 tile, 256 threads (4 waves, each 64x32 = 4x2 MFMA_16x16x32_bf16).
__global__ __launch_bounds__(256) void gemm_em(
    const unsigned short* __restrict__ A,
    const unsigned short* __restrict__ W,
    const float* __restrict__ bias,
    float* __restrict__ em)
{
    const int bm = blockIdx.x * 128;
    const int tid = threadIdx.x;
    const int lane = tid & 63;
    const int wave = tid >> 6;
    const int wm = (wave & 1) * 64;
    const int wn = (wave >> 1) * 32;

    __shared__ __align__(16) unsigned short As[128 * 32];  // 8 KB
    __shared__ __align__(16) unsigned short Bs[64 * 32];   // 4 KB

    f32x4 acc[4][2] = {};

    const int srow = tid >> 2;          // 0..63
    const int sk = (tid & 3) * 8;

    const unsigned short* ga0 = A + (size_t)(bm + srow) * 512 + sk;
    const unsigned short* ga1 = A + (size_t)(bm + srow + 64) * 512 + sk;
    const unsigned short* gb  = W + (size_t)srow * 512 + sk;

    unsigned short* lA0 = As + wave * 512;
    unsigned short* lA1 = As + 2048 + wave * 512;
    unsigned short* lB  = Bs + wave * 512;

    for (int kb = 0; kb < 16; kb++) {
        const int k0 = kb * 32;
        __builtin_amdgcn_global_load_lds(
            (const __attribute__((address_space(1))) unsigned int*)(ga0 + k0),
            (__attribute__((address_space(3))) unsigned int*)lA0, 16, 0, 0);
        __builtin_amdgcn_global_load_lds(
            (const __attribute__((address_space(1))) unsigned int*)(ga1 + k0),
            (__attribute__((address_space(3))) unsigned int*)lA1, 16, 0, 0);
        __builtin_amdgcn_global_load_lds(
            (const __attribute__((address_space(1))) unsigned int*)(gb + k0),
            (__attribute__((address_space(3))) unsigned int*)lB, 16, 0, 0);
        __syncthreads();

        short8 af[4], bfr[2];
        #pragma unroll
        for (int i = 0; i < 4; i++)
            af[i]  = *(const short8*)&As[(wm + i * 16 + (lane & 15)) * 32 + (lane >> 4) * 8];
        #pragma unroll
        for (int j = 0; j < 2; j++)
            bfr[j] = *(const short8*)&Bs[(wn + j * 16 + (lane & 15)) * 32 + (lane >> 4) * 8];
        #pragma unroll
        for (int i = 0; i < 4; i++)
            #pragma unroll
            for (int j = 0; j < 2; j++)
                acc[i][j] = __builtin_amdgcn_mfma_f32_16x16x32_bf16(af[i], bfr[j], acc[i][j], 0, 0, 0);
        __syncthreads();
    }

    const int cn = lane & 15;
    const int cr = (lane >> 4) * 4;
    #pragma unroll
    for (int j = 0; j < 2; j++) {
        const int n = wn + j * 16 + cn;
        if (n < KK) {
            const float bv = bias[n];
            #pragma unroll
            for (int i = 0; i < 4; i++) {
                #pragma unroll
                for (int r = 0; r < 4; r++) {
                    const int m = bm + wm + i * 16 + cr + r;
                    em[(size_t)m * KK + n] = acc[i][j][r] + bv;
                }
            }
        }
    }
}

// ---------- LSTM recurrence: grid (64 batches, 2 dirs), 1024 threads ----------
// R2-PROVEN STRUCTURE (250us, VGPR 52): tid = kq*256 + u; 16 named int4
// register-resident weights; sdot4 inner product; red[] LDS cross-kq
// reduction; epilogue on kq==0 waves only (4 waves, 1/SIMD).
// LESSONS: R9 full-K/thread (64 int4) -> spill, 417us. R10 intra-wave quad
// split -> epilogue issued by ALL 16 waves (exec-mask saves nothing), 401us.
// Keep the serial epilogue on FEW waves; others idle at barrier for free.
__global__ __launch_bounds__(1024, 4) void lstm_kernel(
    const unsigned short* __restrict__ zin_f, const unsigned short* __restrict__ zin_b,
    const int* __restrict__ WQf, const int* __restrict__ WQb,
    const float* __restrict__ Sf, const float* __restrict__ Sb,
    unsigned short* __restrict__ h_out)  // (T,B,512) bf16; fwd cols [0:256), bwd [256:512)
{
    const int dir = blockIdx.y;
    const unsigned short* zin = dir ? zin_b : zin_f;
    const int*   WQ = dir ? WQb : WQf;
    const float* S  = dir ? Sb  : Sf;
    const int off = dir ? HH : 0;

    const int b = blockIdx.x;
    const int tid = threadIdx.x;
    const int u  = tid & 255;
    const int kq = tid >> 8;            // wave-uniform

    __shared__ __align__(16) unsigned char hq8[2][HH];  // int8 h, double-buffered
    __shared__ int4 red[3][HH];                          // cross-kq partial sums

    // ---- preload this thread's 256 B of int8 weights into 16 named int4 regs ----
    const int4* wp = (const int4*)WQ + kq * 16 * 256 + u;
    const int4 w0  = wp[ 0 * 256], w1  = wp[ 1 * 256], w2  = wp[ 2 * 256], w3  = wp[ 3 * 256];
    const int4 w4  = wp[ 4 * 256], w5  = wp[ 5 * 256], w6  = wp[ 6 * 256], w7  = wp[ 7 * 256];
    const int4 w8  = wp[ 8 * 256], w9  = wp[ 9 * 256], w10 = wp[10 * 256], w11 = wp[11 * 256];
    const int4 w12 = wp[12 * 256], w13 = wp[13 * 256], w14 = wp[14 * 256], w15 = wp[15 * 256];

    float4 sc = make_float4(0.f, 0.f, 0.f, 0.f);
    if (kq == 0) {
        sc = *(const float4*)(S + 4 * u);
        const float inv127 = 1.0f / 127.0f;
        sc.x *= inv127; sc.y *= inv127; sc.z *= inv127; sc.w *= inv127;
    }
    float c = 0.0f;
    int cur = 0;
    if (tid < 128) ((unsigned int*)hq8)[tid] = 0u;   // zero both buffers
    __syncthreads();

    for (int ts = 0; ts < TT; ts++) {
        const int tt = dir ? (TT - 1 - ts) : ts;
        const int row = tt * BB + b;

        // issue zin load early: latency hides under the dot phase
        ushort4 zv = make_ushort4(0, 0, 0, 0);
        if (kq == 0) zv = *(const ushort4*)(zin + row * FH + 4 * u);

        // h broadcast: 16 dwords (64 int8) via 4x b128, wave-uniform address
        const int4* hv = (const int4*)&hq8[cur][kq * 64];
        const int4 hA = hv[0], hB = hv[1], hC = hv[2], hD = hv[3];

        int a0 = 0, a1 = 0, a2 = 0, a3 = 0;
        lstm_dot(hA.x, w0,  a0, a1, a2, a3);
        lstm_dot(hA.y, w1,  a0, a1, a2, a3);
        lstm_dot(hA.z, w2,  a0, a1, a2, a3);
        lstm_dot(hA.w, w3,  a0, a1, a2, a3);
        lstm_dot(hB.x, w4,  a0, a1, a2, a3);
        lstm_dot(hB.y, w5,  a0, a1, a2, a3);
        lstm_dot(hB.z, w6,  a0, a1, a2, a3);
        lstm_dot(hB.w, w7,  a0, a1, a2, a3);
        lstm_dot(hC.x, w8,  a0, a1, a2, a3);
        lstm_dot(hC.y, w9,  a0, a1, a2, a3);
        lstm_dot(hC.z, w10, a0, a1, a2, a3);
        lstm_dot(hC.w, w11, a0, a1, a2, a3);
        lstm_dot(hD.x, w12, a0, a1, a2, a3);
        lstm_dot(hD.y, w13, a0, a1, a2, a3);
        lstm_dot(hD.z, w14, a0, a1, a2, a3);
        lstm_dot(hD.w, w15, a0, a1, a2, a3);

        if (kq) red[kq - 1][u] = make_int4(a0, a1, a2, a3);
        __syncthreads();

        if (kq == 0) {
            const int4 r0 = red[0][u], r1 = red[1][u], r2 = red[2][u];
            const int A0 = a0 + r0.x + r1.x + r2.x;
            const int A1 = a1 + r0.y + r1.y + r2.y;
            const int A2 = a2 + r0.z + r1.z + r2.z;
            const int A3 = a3 + r0.w + r1.w + r2.w;
            const float zi  = (float)A0 * sc.x + bf2f(zv.x);
            const float zf_ = (float)A1 * sc.y + bf2f(zv.y);
            const float zg  = (float)A2 * sc.z + bf2f(zv.z);
            const float zo  = (float)A3 * sc.w + bf2f(zv.w);
            const float cc = sigm(zf_) * c + sigm(zi) * tanh_f(zg);
            c = cc;
            const float hh = sigm(zo) * tanh_f(cc);
            hq8[cur ^ 1][u] = (unsigned char)((int)rintf(hh * 127.0f));
            h_out[row * (2 * HH) + off + u] = f2bf(hh);
        }
        __syncthreads();
        cur ^= 1;
    }
}

// ---------- CRF: one block (1 wave) per batch ----------
__global__ __launch_bounds__(64) void crf_kernel(
    const int* __restrict__ text, const int* __restrict__ sbj,
    const float* __restrict__ em,
    const float* __restrict__ start_t, const float* __restrict__ end_t,
    const float* __restrict__ trans, float* __restrict__ accum)
{
    const int b = blockIdx.x;
    const int tid = threadIdx.x;
    __shared__ float tr[KK * KK];
    __shared__ float sc[2][KK];
    for (int x = tid; x < KK * KK; x += 64) tr[x] = trans[x];

    int cnt = 0;
    for (int t = tid; t < TT; t += 64) cnt += (text[b * TT + t] != 0) ? 1 : 0;
    #pragma unroll
    for (int s = 32; s > 0; s >>= 1) cnt += __shfl_down(cnt, s, 64);
    const int len = __shfl(cnt, 0, 64);

    __syncthreads();

    float part = 0.f;
    for (int t = tid; t < TT; t += 64) {
        if (t >= 1 && t < len) {
            const int tg = sbj[b * TT + t];
            const int tp = sbj[b * TT + t - 1];
            part += em[(t * BB + b) * KK + tg] + tr[tp * KK + tg];
        }
    }
    #pragma unroll
    for (int s = 32; s > 0; s >>= 1) part += __shfl_down(part, s, 64);

    if (tid < KK) sc[0][tid] = start_t[tid] + em[b * KK + tid];
    __syncthreads();
    int cur = 0;
    for (int t = 1; t < len; t++) {
        float nv = 0.f;
        if (tid < KK) {
            float mx = -1e30f;
            for (int k1 = 0; k1 < KK; k1++)
                mx = fmaxf(mx, sc[cur][k1] + tr[k1 * KK + tid]);
            float s = 0.f;
            for (int k1 = 0; k1 < KK; k1++)
                s += __expf(sc[cur][k1] + tr[k1 * KK + tid] - mx);
            nv = mx + __logf(s) + em[(t * BB + b) * KK + tid];
        }
        if (tid < KK) sc[cur ^ 1][tid] = nv;
        __syncthreads();
        cur ^= 1;
    }

    if (tid == 0) {
        const int tg0 = sbj[b * TT];
        const int tgl = sbj[b * TT + len - 1];
        const float num = start_t[tg0] + em[b * KK + tg0] + part + end_t[tgl];
        float mx = -1e30f;
        for (int k = 0; k < KK; k++) mx = fmaxf(mx, sc[cur][k] + end_t[k]);
        float s = 0.f;
        for (int k = 0; k < KK; k++) s += __expf(sc[cur][k] + end_t[k] - mx);
        const float logZ = mx + __logf(s);
        atomicAdd(&accum[0], num - logZ);
        atomicAdd(&accum[1], (float)len);
    }
}

__global__ void init_kernel(float* __restrict__ accum) {
    if (threadIdx.x < 2) accum[threadIdx.x] = 0.0f;
}
__global__ void final_kernel(const float* __restrict__ accum, float* __restrict__ out) {
    out[0] = -(accum[0] / accum[1]);
}

// ---------- launch ----------
extern "C" void kernel_launch(void* const* d_in, const int* in_sizes, int n_in,
                              void* d_out, int out_size, void* d_ws, size_t ws_size,
                              hipStream_t stream)
{
    (void)in_sizes; (void)n_in; (void)out_size; (void)ws_size;
    const int*   text  = (const int*)d_in[0];
    const int*   sbj   = (const int*)d_in[1];
    const float* emb   = (const float*)d_in[2];
    const float* Wih0f = (const float*)d_in[3];
    const float* Whh0f = (const float*)d_in[4];
    const float* b0f   = (const float*)d_in[5];
    const float* Wih0b = (const float*)d_in[6];
    const float* Whh0b = (const float*)d_in[7];
    const float* b0b   = (const float*)d_in[8];
    const float* Wih1f = (const float*)d_in[9];
    const float* Whh1f = (const float*)d_in[10];
    const float* b1f   = (const float*)d_in[11];
    const float* Wih1b = (const float*)d_in[12];
    const float* Whh1b = (const float*)d_in[13];
    const float* b1b   = (const float*)d_in[14];
    const float* Wsbj  = (const float*)d_in[15];
    const float* bsbj  = (const float*)d_in[16];
    const float* start_t = (const float*)d_in[17];
    const float* end_t   = (const float*)d_in[18];
    const float* trans   = (const float*)d_in[19];

    // workspace map (bytes), max ~102.84 MB. Overlaps (stream-ordered lifetimes):
    //   Wb0f/Wb0b in h0 region (dead before lstm0 writes h0)
    //   Abf, Wb1f/Wb1b in h1 region (dead before lstm1 writes h1)
    //   em reuses zf (dead after lstm1)
    char* ws = (char*)d_ws;
    unsigned short* zf   = (unsigned short*)(ws + 0);           // 32 MiB
    unsigned short* zb   = (unsigned short*)(ws + 33554432);    // 32 MiB
    unsigned short* h0   = (unsigned short*)(ws + 67108864);    // 16 MiB
    unsigned short* h1   = (unsigned short*)(ws + 83886080);    // 16 MiB
    unsigned short* Wb0f = (unsigned short*)(ws + 67108864);    // 1024x320 bf16
    unsigned short* Wb0b = (unsigned short*)(ws + 67764224);
    unsigned short* Abf  = (unsigned short*)(ws + 83886080);    // 16384x320 bf16 (10 MiB)
    unsigned short* Wb1f = (unsigned short*)(ws + 94371840);    // 1024x512 bf16
    unsigned short* Wb1b = (unsigned short*)(ws + 95420416);
    unsigned int*   WQ   = (unsigned int*)(ws + 100663296);     // 4 x 256 KiB int8 weights
    float*          Sq   = (float*)(ws + 101711872);            // 4 x 4 KiB scales
    unsigned short* WsbjB = (unsigned short*)(ws + 102760448);  // 64x512 bf16 (64 KiB)
    float*          acc  = (float*)(ws + 102836224);            // 8 B
    float*           em  = (float*)(ws + 0);                    // 2.4 MiB (over zf)
    float* out = (float*)d_out;

    const int* WQ0f = (const int*)(WQ + 0 * 65536);
    const int* WQ0b = (const int*)(WQ + 1 * 65536);
    const int* WQ1f = (const int*)(WQ + 2 * 65536);
    const int* WQ1b = (const int*)(WQ + 3 * 65536);
    const float* S0f = Sq + 0 * 1024;
    const float* S0b = Sq + 1 * 1024;
    const float* S1f = Sq + 2 * 1024;
    const float* S1b = Sq + 3 * 1024;

    init_kernel<<<1, 64, 0, stream>>>(acc);
    conv_scale<<<dim3(4096), 64, 0, stream>>>(Whh0f, Whh0b, Whh1f, Whh1b, Sq);
    conv_wq<<<dim3(1024), 256, 0, stream>>>(Whh0f, Whh0b, Whh1f, Whh1b, Sq, WQ);
    conv_wsbj_bf<<<dim3(128), 256, 0, stream>>>(Wsbj, WsbjB);
    conv_gather<<<dim3(MTOT), 320, 0, stream>>>(text, emb, Abf);
    conv_w<<<dim3(1280), 256, 0, stream>>>(Wih0f, Wb0f, DD, KP0, 1024 * KP0);
    conv_w<<<dim3(1280), 256, 0, stream>>>(Wih0b, Wb0b, DD, KP0, 1024 * KP0);
    conv_w<<<dim3(2048), 256, 0, stream>>>(Wih1f, Wb1f, 512, 512, 1024 * 512);
    conv_w<<<dim3(2048), 256, 0, stream>>>(Wih1b, Wb1b, 512, 512, 1024 * 512);

    // layer 0 input projection (MFMA), f+b in one dispatch
    gemm_mfma2<<<dim3(128, 8, 2), 256, 0, stream>>>(Abf, Wb0f, Wb0b, b0f, b0b, zf, zb, KP0);
    lstm_kernel<<<dim3(BB, 2), 1024, 0, stream>>>(zf, zb, WQ0f, WQ0b, S0f, S0b, h0);
    // layer 1 input projection (MFMA), f+b in one dispatch
    gemm_mfma2<<<dim3(128, 8, 2), 256, 0, stream>>>(h0, Wb1f, Wb1b, b1f, b1b, zf, zb, 512);
    lstm_kernel<<<dim3(BB, 2), 1024, 0, stream>>>(zf, zb, WQ1f, WQ1b, S1f, S1b, h1);

    gemm_em<<<dim3(128), 256, 0, stream>>>(h1, WsbjB, bsbj, em);
    crf_kernel<<<BB, 64, 0, stream>>>(text, sbj, em, start_t, end_t, trans, acc);
    final_kernel<<<1, 1, 0, stream>>>(acc, out);
}

// Round 7
// 968.867 us; speedup vs baseline: 1.4088x; 1.0507x over previous
//
#include <hip/hip_runtime.h>
#include <math.h>

// Problem constants
#define TT 256      // sequence length
#define BB 64       // batch
#define DD 300      // embedding dim
#define KP0 320     // layer-0 K padded to multiple of 32
#define HH 256      // hidden
#define KK 37       // CRF states
#define FH 1024     // 4*H
#define MTOT (TT*BB) // 16384 rows, time-major r = t*64 + b

typedef __attribute__((ext_vector_type(8))) short short8;  // 8 bf16 (4 VGPR) MFMA A/B frag
typedef __attribute__((ext_vector_type(4))) float f32x4;   // MFMA C/D frag

// ---------- bf16 helpers ----------
__device__ __forceinline__ float bf2f(unsigned short u) {
    union { float f; unsigned int i; } v; v.i = ((unsigned int)u) << 16; return v.f;
}
__device__ __forceinline__ unsigned short f2bf(float f) {
    union { float f; unsigned int i; } v; v.f = f;
    unsigned int i = v.i;
    unsigned int r = (i + 0x7FFFu + ((i >> 16) & 1u)) >> 16; // RNE
    return (unsigned short)r;
}
__device__ __forceinline__ float sigm(float x)   { return 1.0f / (1.0f + __expf(-x)); }
__device__ __forceinline__ float tanh_f(float x) { return 2.0f / (1.0f + __expf(-2.0f * x)) - 1.0f; }

// signed byte extract (compiler -> v_bfe_i32)
__device__ __forceinline__ int sb0(int w) { return (w << 24) >> 24; }
__device__ __forceinline__ int sb1(int w) { return (w << 16) >> 24; }
__device__ __forceinline__ int sb2(int w) { return (w <<  8) >> 24; }
__device__ __forceinline__ int sb3(int w) { return  w        >> 24; }

#if defined(__has_builtin)
#if __has_builtin(__builtin_amdgcn_sdot4)
#define HAVE_SDOT4 1
#endif
#endif

// 4x int8 dot product: c += dot(a.bytes, b.bytes)
__device__ __forceinline__ int dot4i8(int a, int b, int c) {
#ifdef HAVE_SDOT4
    return __builtin_amdgcn_sdot4(a, b, c, false);
#else
    return c + sb0(a) * sb0(b) + sb1(a) * sb1(b) + sb2(a) * sb2(b) + sb3(a) * sb3(b);
#endif
}

// accumulate 4 gates for one h-dword against one weight int4
__device__ __forceinline__ void lstm_dot(int hw, int4 wv, int& a0, int& a1, int& a2, int& a3) {
    a0 = dot4i8(hw, wv.x, a0);
    a1 = dot4i8(hw, wv.y, a1);
    a2 = dot4i8(hw, wv.z, a2);
    a3 = dot4i8(hw, wv.w, a3);
}

// barrier that waits only on LDS ops (lgkmcnt), NOT on global loads/stores.
// __syncthreads would drain vmcnt(0) -> exposes HBM latency of in-flight
// zin loads / h_out stores at every step (T4 lesson: never drain vmcnt to 0
// in a hot loop). LDS producer->consumer ordering is fully preserved.
__device__ __forceinline__ void barrier_lgkm() {
    asm volatile("s_waitcnt lgkmcnt(0)\n\ts_barrier" ::: "memory");
}

// permute gate-major col (g*256+unit) -> interleaved (unit*4+g)
__device__ __forceinline__ int perm_col(int nn) { return ((nn & 255) << 2) | (nn >> 8); }

// ---------- prep: per-row quant step S[m][u*4+g] = max_k |Whh[m][(g*256+u)*256+k]| / 127 ----------
__global__ __launch_bounds__(64) void conv_scale(
    const float* __restrict__ w0f, const float* __restrict__ w0b,
    const float* __restrict__ w1f, const float* __restrict__ w1b,
    float* __restrict__ S)   // 4 x 1024
{
    const int m = blockIdx.x >> 10;
    const int r = blockIdx.x & 1023;          // r = g*256 + u
    const float* W = m == 0 ? w0f : m == 1 ? w0b : m == 2 ? w1f : w1b;
    const int t = threadIdx.x;
    float mx = 0.f;
    for (int k = t; k < HH; k += 64) mx = fmaxf(mx, fabsf(W[r * HH + k]));
    #pragma unroll
    for (int s = 32; s > 0; s >>= 1) mx = fmaxf(mx, __shfl_down(mx, s, 64));
    if (t == 0) {
        const int g = r >> 8, u = r & 255;
        S[m * 1024 + u * 4 + g] = fmaxf(mx, 1e-20f) / 127.0f;
    }
}

// ---------- prep: quantize Whh -> WQ int8, word[((kq*16+j)*256+u)*4+g] = 4 k (k0=kq*64+j*4) ----------
// (R2-proven layout; lstm reads wp = WQ_int4 + kq*16*256 + u, stride j*256.)
__global__ __launch_bounds__(256) void conv_wq(
    const float* __restrict__ w0f, const float* __restrict__ w0b,
    const float* __restrict__ w1f, const float* __restrict__ w1b,
    const float* __restrict__ S, unsigned int* __restrict__ WQ)
{
    const int idx = blockIdx.x * 256 + threadIdx.x;     // 0 .. 4*65536-1
    const int m = idx >> 16;
    const int r = idx & 65535;
    const float* W = m == 0 ? w0f : m == 1 ? w0b : m == 2 ? w1f : w1b;
    const int g  = r & 3;
    const int u  = (r >> 2) & 255;
    const int j  = (r >> 10) & 15;
    const int kq = r >> 14;
    const int k0 = kq * 64 + j * 4;
    const float s = S[m * 1024 + u * 4 + g];
    const float4 wv = *(const float4*)(W + (g * HH + u) * HH + k0);
    int q0 = (int)rintf(wv.x / s), q1 = (int)rintf(wv.y / s);
    int q2 = (int)rintf(wv.z / s), q3 = (int)rintf(wv.w / s);
    q0 = max(-127, min(127, q0)); q1 = max(-127, min(127, q1));
    q2 = max(-127, min(127, q2)); q3 = max(-127, min(127, q3));
    WQ[idx] = (unsigned int)(q0 & 0xff) | ((unsigned int)(q1 & 0xff) << 8) |
              ((unsigned int)(q2 & 0xff) << 16) | ((unsigned int)(q3 & 0xff) << 24);
}

// ---------- prep: Wsbj f32 (37x512) -> bf16 padded (64x512), rows>=37 zero ----------
__global__ __launch_bounds__(256) void conv_wsbj_bf(
    const float* __restrict__ Wsbj, unsigned short* __restrict__ WB)
{
    const int idx = blockIdx.x * 256 + threadIdx.x;   // 0 .. 64*512-1
    if (idx >= 64 * 512) return;
    const int r = idx >> 9, cidx = idx & 511;
    WB[idx] = (r < KK) ? f2bf(Wsbj[r * 512 + cidx]) : (unsigned short)0;
}

// ---------- prep: gather embedding rows -> Abf bf16 [16384][320] (zero-pad k>=300) ----------
__global__ __launch_bounds__(320) void conv_gather(
    const int* __restrict__ text, const float* __restrict__ emb,
    unsigned short* __restrict__ Abf)
{
    const int r = blockIdx.x;
    const int k = threadIdx.x;
    const int t = r >> 6, b = r & 63;
    const int idx = text[b * TT + t];
    Abf[r * KP0 + k] = (k < DD) ? f2bf(emb[(size_t)idx * DD + k]) : (unsigned short)0;
}

// ---------- prep: 4x W f32 -> bf16 zero-padded, merged into one dispatch ----------
// z=0,1: Wih0f/b (300 -> 320); z=2,3: Wih1f/b (512 -> 512)
__global__ __launch_bounds__(256) void conv_w4(
    const float* __restrict__ s0, const float* __restrict__ s1,
    const float* __restrict__ s2, const float* __restrict__ s3,
    unsigned short* __restrict__ d0, unsigned short* __restrict__ d1,
    unsigned short* __restrict__ d2, unsigned short* __restrict__ d3)
{
    const int z = blockIdx.y;
    const float* src = z == 0 ? s0 : z == 1 ? s1 : z == 2 ? s2 : s3;
    unsigned short* dst = z == 0 ? d0 : z == 1 ? d1 : z == 2 ? d2 : d3;
    const int kin   = z < 2 ? DD  : 512;
    const int kout  = z < 2 ? KP0 : 512;
    const int total = 1024 * kout;
    const int idx = blockIdx.x * 256 + threadIdx.x;
    if (idx >= total) return;
    const int rr = idx / kout, k = idx - rr * kout;
    dst[idx] = (k < kin) ? f2bf(src[rr * kin + k]) : (unsigned short)0;
}

// ---------- MFMA GEMM (f+b merged on blockIdx.z): out_z = A @ W_z^T + bias_z ----------
// 128x128 tile, 256 threads (4 waves, each 64x64 = 4x4 MFMA_16x16x32_bf16).
// Staging via global_load_lds width=16 (linear LDS layout = lane order, no padding).
__global__ __launch_bounds__(256) void gemm_mfma2(
    const unsigned short* __restrict__ A,
    const unsigned short* __restrict__ Wf,
    const unsigned short* __restrict__ Wb,
    const float* __restrict__ biasf,
    const float* __restrict__ biasb,
    unsigned short* __restrict__ outf,
    unsigned short* __restrict__ outb,
    int lda)
{
    const unsigned short* W = blockIdx.z ? Wb : Wf;
    const float* bias        = blockIdx.z ? biasb : biasf;
    unsigned short* out      = blockIdx.z ? outb : outf;

    const int bm = blockIdx.x * 128;
    const int bn = blockIdx.y * 128;
    const int tid = threadIdx.x;
    const int lane = tid & 63;
    const int wave = tid >> 6;
    const int wm = (wave & 1) * 64;
    const int wn = (wave >> 1) * 64;

    __shared__ __align__(16) unsigned short As[128 * 32];  // [row][k] 8 KB
    __shared__ __align__(16) unsigned short Bs[128 * 32];  // [wrow][k] 8 KB

    f32x4 acc[4][4] = {};

    const int srow = tid >> 2;          // 0..63
    const int sk = (tid & 3) * 8;       // k element offset (16 B granules)

    const unsigned short* ga0 = A + (size_t)(bm + srow) * lda + sk;
    const unsigned short* ga1 = A + (size_t)(bm + srow + 64) * lda + sk;
    const unsigned short* gb0 = W + (size_t)(bn + srow) * lda + sk;
    const unsigned short* gb1 = W + (size_t)(bn + srow + 64) * lda + sk;

    unsigned short* lA0 = As + wave * 512;
    unsigned short* lA1 = As + 2048 + wave * 512;
    unsigned short* lB0 = Bs + wave * 512;
    unsigned short* lB1 = Bs + 2048 + wave * 512;

    const int kiters = lda >> 5;
    for (int kb = 0; kb < kiters; kb++) {
        const int k0 = kb * 32;
        __builtin_amdgcn_global_load_lds(
            (const __attribute__((address_space(1))) unsigned int*)(ga0 + k0),
            (__attribute__((address_space(3))) unsigned int*)lA0, 16, 0, 0);
        __builtin_amdgcn_global_load_lds(
            (const __attribute__((address_space(1))) unsigned int*)(ga1 + k0),
            (__attribute__((address_space(3))) unsigned int*)lA1, 16, 0, 0);
        __builtin_amdgcn_global_load_lds(
            (const __attribute__((address_space(1))) unsigned int*)(gb0 + k0),
            (__attribute__((address_space(3))) unsigned int*)lB0, 16, 0, 0);
        __builtin_amdgcn_global_load_lds(
            (const __attribute__((address_space(1))) unsigned int*)(gb1 + k0),
            (__attribute__((address_space(3))) unsigned int*)lB1, 16, 0, 0);
        __syncthreads();

        short8 af[4], bfr[4];
        #pragma unroll
        for (int i = 0; i < 4; i++) {
            af[i]  = *(const short8*)&As[(wm + i * 16 + (lane & 15)) * 32 + (lane >> 4) * 8];
            bfr[i] = *(const short8*)&Bs[(wn + i * 16 + (lane & 15)) * 32 + (lane >> 4) * 8];
        }
        #pragma unroll
        for (int i = 0; i < 4; i++)
            #pragma unroll
            for (int j = 0; j < 4; j++)
                acc[i][j] = __builtin_amdgcn_mfma_f32_16x16x32_bf16(af[i], bfr[j], acc[i][j], 0, 0, 0);
        __syncthreads();
    }

    // C/D: col = lane&15, row = (lane>>4)*4 + reg  [measured m89/m91]
    const int cn = lane & 15;
    const int cr = (lane >> 4) * 4;
    #pragma unroll
    for (int j = 0; j < 4; j++) {
        const int n = bn + wn + j * 16 + cn;
        const float bv = bias[n];
        const int pc = perm_col(n);
        #pragma unroll
        for (int i = 0; i < 4; i++) {
            #pragma unroll
            for (int r = 0; r < 4; r++) {
                const int m = bm + wm + i * 16 + cr + r;
                out[(size_t)m * FH + pc] = f2bf(acc[i][j][r] + bv);
            }
        }
    }
}

// ---------- Emission GEMM: em = h1(16384x512 bf16) @ WsbjB(64x512 bf16)^T + bias, f32 out ----------
// 128x64 tile, 256 threads (4 waves, each 64x32 = 4x2 MFMA_16x16x32_bf16).
__global__ __launch_bounds__(256) void gemm_em(
    const unsigned short* __restrict__ A,
    const unsigned short* __restrict__ W,
    const float* __restrict__ bias,
    float* __restrict__ em)
{
    const int bm = blockIdx.x * 128;
    const int tid = threadIdx.x;
    const int lane = tid & 63;
    const int wave = tid >> 6;
    const int wm = (wave & 1) * 64;
    const int wn = (wave >> 1) * 32;

    __shared__ __align__(16) unsigned short As[128 * 32];  // 8 KB
    __shared__ __align__(16) unsigned short Bs[64 * 32];   // 4 KB

    f32x4 acc[4][2] = {};

    const int srow = tid >> 2;          // 0..63
    const int sk = (tid & 3) * 8;

    const unsigned short* ga0 = A + (size_t)(bm + srow) * 512 + sk;
    const unsigned short* ga1 = A + (size_t)(bm + srow + 64) * 512 + sk;
    const unsigned short* gb  = W + (size_t)srow * 512 + sk;

    unsigned short* lA0 = As + wave * 512;
    unsigned short* lA1 = As + 2048 + wave * 512;
    unsigned short* lB  = Bs + wave * 512;

    for (int kb = 0; kb < 16; kb++) {
        const int k0 = kb * 32;
        __builtin_amdgcn_global_load_lds(
            (const __attribute__((address_space(1))) unsigned int*)(ga0 + k0),
            (__attribute__((address_space(3))) unsigned int*)lA0, 16, 0, 0);
        __builtin_amdgcn_global_load_lds(
            (const __attribute__((address_space(1))) unsigned int*)(ga1 + k0),
            (__attribute__((address_space(3))) unsigned int*)lA1, 16, 0, 0);
        __builtin_amdgcn_global_load_lds(
            (const __attribute__((address_space(1))) unsigned int*)(gb + k0),
            (__attribute__((address_space(3))) unsigned int*)lB, 16, 0, 0);
        __syncthreads();

        short8 af[4], bfr[2];
        #pragma unroll
        for (int i = 0; i < 4; i++)
            af[i]  = *(const short8*)&As[(wm + i * 16 + (lane & 15)) * 32 + (lane >> 4) * 8];
        #pragma unroll
        for (int j = 0; j < 2; j++)
            bfr[j] = *(const short8*)&Bs[(wn + j * 16 + (lane & 15)) * 32 + (lane >> 4) * 8];
        #pragma unroll
        for (int i = 0; i < 4; i++)
            #pragma unroll
            for (int j = 0; j < 2; j++)
                acc[i][j] = __builtin_amdgcn_mfma_f32_16x16x32_bf16(af[i], bfr[j], acc[i][j], 0, 0, 0);
        __syncthreads();
    }

    const int cn = lane & 15;
    const int cr = (lane >> 4) * 4;
    #pragma unroll
    for (int j = 0; j < 2; j++) {
        const int n = wn + j * 16 + cn;
        if (n < KK) {
            const float bv = bias[n];
            #pragma unroll
            for (int i = 0; i < 4; i++) {
                #pragma unroll
                for (int r = 0; r < 4; r++) {
                    const int m = bm + wm + i * 16 + cr + r;
                    em[(size_t)m * KK + n] = acc[i][j][r] + bv;
                }
            }
        }
    }
}

// ---------- LSTM recurrence: grid (64 batches, 2 dirs), 1024 threads ----------
// R2-PROVEN STRUCTURE (250us, VGPR 52) + R7 changes:
//  (1) in-loop barriers are lgkmcnt-only (barrier_lgkm) -- __syncthreads drains
//      vmcnt(0), exposing ~250-900 cyc of zin HBM latency at barrier 1 every
//      step. LDS ordering (red/hq8) needs only lgkmcnt.
//  (2) zin prefetched ONE STEP AHEAD (clamped); with no vmcnt drain at
//      barriers, the load has ~2300 cyc to complete before use.
// LESSONS: R9 full-K/thread -> spill (417us). R10 intra-wave quad-split ->
// epilogue issued by ALL 16 waves (401us). Epilogue stays on 4 kq0 waves.
__global__ __launch_bounds__(1024, 4) void lstm_kernel(
    const unsigned short* __restrict__ zin_f, const unsigned short* __restrict__ zin_b,
    const int* __restrict__ WQf, const int* __restrict__ WQb,
    const float* __restrict__ Sf, const float* __restrict__ Sb,
    unsigned short* __restrict__ h_out)  // (T,B,512) bf16; fwd cols [0:256), bwd [256:512)
{
    const int dir = blockIdx.y;
    const unsigned short* zin = dir ? zin_b : zin_f;
    const int*   WQ = dir ? WQb : WQf;
    const float* S  = dir ? Sb  : Sf;
    const int off = dir ? HH : 0;

    const int b = blockIdx.x;
    const int tid = threadIdx.x;
    const int u  = tid & 255;
    const int kq = tid >> 8;            // wave-uniform

    __shared__ __align__(16) unsigned char hq8[2][HH];  // int8 h, double-buffered
    __shared__ int4 red[3][HH];                          // cross-kq partial sums

    // ---- preload this thread's 256 B of int8 weights into 16 named int4 regs ----
    const int4* wp = (const int4*)WQ + kq * 16 * 256 + u;
    const int4 w0  = wp[ 0 * 256], w1  = wp[ 1 * 256], w2  = wp[ 2 * 256], w3  = wp[ 3 * 256];
    const int4 w4  = wp[ 4 * 256], w5  = wp[ 5 * 256], w6  = wp[ 6 * 256], w7  = wp[ 7 * 256];
    const int4 w8  = wp[ 8 * 256], w9  = wp[ 9 * 256], w10 = wp[10 * 256], w11 = wp[11 * 256];
    const int4 w12 = wp[12 * 256], w13 = wp[13 * 256], w14 = wp[14 * 256], w15 = wp[15 * 256];

    float4 sc = make_float4(0.f, 0.f, 0.f, 0.f);
    if (kq == 0) {
        sc = *(const float4*)(S + 4 * u);
        const float inv127 = 1.0f / 127.0f;
        sc.x *= inv127; sc.y *= inv127; sc.z *= inv127; sc.w *= inv127;
    }
    float c = 0.0f;
    int cur = 0;
    if (tid < 128) ((unsigned int*)hq8)[tid] = 0u;   // zero both buffers
    __syncthreads();

    // prefetch z for step 0 (kq0 lanes only)
    ushort4 zv = make_ushort4(0, 0, 0, 0);
    if (kq == 0) {
        const int tt0 = dir ? (TT - 1) : 0;
        zv = *(const ushort4*)(zin + (tt0 * BB + b) * FH + 4 * u);
    }

    for (int ts = 0; ts < TT; ts++) {
        const int tt = dir ? (TT - 1 - ts) : ts;
        const int row = tt * BB + b;

        // issue NEXT step's zin load now; consumed next iteration (~2300 cyc away)
        ushort4 zv_n = make_ushort4(0, 0, 0, 0);
        if (kq == 0) {
            const int ts_n = (ts + 1 < TT) ? (ts + 1) : ts;
            const int tt_n = dir ? (TT - 1 - ts_n) : ts_n;
            zv_n = *(const ushort4*)(zin + (tt_n * BB + b) * FH + 4 * u);
        }

        // h broadcast: 16 dwords (64 int8) via 4x b128, wave-uniform address
        const int4* hv = (const int4*)&hq8[cur][kq * 64];
        const int4 hA = hv[0], hB = hv[1], hC = hv[2], hD = hv[3];

        int a0 = 0, a1 = 0, a2 = 0, a3 = 0;
        lstm_dot(hA.x, w0,  a0, a1, a2, a3);
        lstm_dot(hA.y, w1,  a0, a1, a2, a3);
        lstm_dot(hA.z, w2,  a0, a1, a2, a3);
        lstm_dot(hA.w, w3,  a0, a1, a2, a3);
        lstm_dot(hB.x, w4,  a0, a1, a2, a3);
        lstm_dot(hB.y, w5,  a0, a1, a2, a3);
        lstm_dot(hB.z, w6,  a0, a1, a2, a3);
        lstm_dot(hB.w, w7,  a0, a1, a2, a3);
        lstm_dot(hC.x, w8,  a0, a1, a2, a3);
        lstm_dot(hC.y, w9,  a0, a1, a2, a3);
        lstm_dot(hC.z, w10, a0, a1, a2, a3);
        lstm_dot(hC.w, w11, a0, a1, a2, a3);
        lstm_dot(hD.x, w12, a0, a1, a2, a3);
        lstm_dot(hD.y, w13, a0, a1, a2, a3);
        lstm_dot(hD.z, w14, a0, a1, a2, a3);
        lstm_dot(hD.w, w15, a0, a1, a2, a3);

        if (kq) red[kq - 1][u] = make_int4(a0, a1, a2, a3);
        barrier_lgkm();

        if (kq == 0) {
            const int4 r0 = red[0][u], r1 = red[1][u], r2 = red[2][u];
            const int A0 = a0 + r0.x + r1.x + r2.x;
            const int A1 = a1 + r0.y + r1.y + r2.y;
            const int A2 = a2 + r0.z + r1.z + r2.z;
            const int A3 = a3 + r0.w + r1.w + r2.w;
            const float zi  = (float)A0 * sc.x + bf2f(zv.x);
            const float zf_ = (float)A1 * sc.y + bf2f(zv.y);
            const float zg  = (float)A2 * sc.z + bf2f(zv.z);
            const float zo  = (float)A3 * sc.w + bf2f(zv.w);
            const float cc = sigm(zf_) * c + sigm(zi) * tanh_f(zg);
            c = cc;
            const float hh = sigm(zo) * tanh_f(cc);
            hq8[cur ^ 1][u] = (unsigned char)((int)rintf(hh * 127.0f));
            h_out[row * (2 * HH) + off + u] = f2bf(hh);
        }
        barrier_lgkm();
        cur ^= 1;
        zv = zv_n;
    }
}

// ---------- CRF: one block (1 wave) per batch ----------
// R7: trans column for this thread's target state cached in 37 unrolled
// registers (t-invariant); max/sum passes fused via register v[37]
// (all indices compile-time -> registers, rule #20).
__global__ __launch_bounds__(64) void crf_kernel(
    const int* __restrict__ text, const int* __restrict__ sbj,
    const float* __restrict__ em,
    const float* __restrict__ start_t, const float* __restrict__ end_t,
    const float* __restrict__ trans, float* __restrict__ accum)
{
    const int b = blockIdx.x;
    const int tid = threadIdx.x;
    __shared__ float tr[KK * KK];
    __shared__ float sc[2][KK];
    for (int x = tid; x < KK * KK; x += 64) tr[x] = trans[x];

    int cnt = 0;
    for (int t = tid; t < TT; t += 64) cnt += (text[b * TT + t] != 0) ? 1 : 0;
    #pragma unroll
    for (int s = 32; s > 0; s >>= 1) cnt += __shfl_down(cnt, s, 64);
    const int len = __shfl(cnt, 0, 64);

    __syncthreads();

    float part = 0.f;
    for (int t = tid; t < TT; t += 64) {
        if (t >= 1 && t < len) {
            const int tg = sbj[b * TT + t];
            const int tp = sbj[b * TT + t - 1];
            part += em[(t * BB + b) * KK + tg] + tr[tp * KK + tg];
        }
    }
    #pragma unroll
    for (int s = 32; s > 0; s >>= 1) part += __shfl_down(part, s, 64);

    // cache this thread's trans column: tc[k1] = tr[k1][tid]  (t-invariant)
    float tc[KK];
    #pragma unroll
    for (int k1 = 0; k1 < KK; k1++) tc[k1] = (tid < KK) ? tr[k1 * KK + tid] : 0.f;

    if (tid < KK) sc[0][tid] = start_t[tid] + em[b * KK + tid];
    __syncthreads();
    int cur = 0;
    for (int t = 1; t < len; t++) {
        float nv = 0.f;
        if (tid < KK) {
            const float ev = em[(t * BB + b) * KK + tid];  // issue early
            float v[KK];
            float mx = -1e30f;
            #pragma unroll
            for (int k1 = 0; k1 < KK; k1++) {
                v[k1] = sc[cur][k1] + tc[k1];
                mx = fmaxf(mx, v[k1]);
            }
            float s = 0.f;
            #pragma unroll
            for (int k1 = 0; k1 < KK; k1++)
                s += __expf(v[k1] - mx);
            nv = mx + __logf(s) + ev;
        }
        if (tid < KK) sc[cur ^ 1][tid] = nv;
        __syncthreads();
        cur ^= 1;
    }

    if (tid == 0) {
        const int tg0 = sbj[b * TT];
        const int tgl = sbj[b * TT + len - 1];
        const float num = start_t[tg0] + em[b * KK + tg0] + part + end_t[tgl];
        float mx = -1e30f;
        for (int k = 0; k < KK; k++) mx = fmaxf(mx, sc[cur][k] + end_t[k]);
        float s = 0.f;
        for (int k = 0; k < KK; k++) s += __expf(sc[cur][k] + end_t[k] - mx);
        const float logZ = mx + __logf(s);
        atomicAdd(&accum[0], num - logZ);
        atomicAdd(&accum[1], (float)len);
    }
}

__global__ void init_kernel(float* __restrict__ accum) {
    if (threadIdx.x < 2) accum[threadIdx.x] = 0.0f;
}
__global__ void final_kernel(const float* __restrict__ accum, float* __restrict__ out) {
    out[0] = -(accum[0] / accum[1]);
}

// ---------- launch ----------
extern "C" void kernel_launch(void* const* d_in, const int* in_sizes, int n_in,
                              void* d_out, int out_size, void* d_ws, size_t ws_size,
                              hipStream_t stream)
{
    (void)in_sizes; (void)n_in; (void)out_size; (void)ws_size;
    const int*   text  = (const int*)d_in[0];
    const int*   sbj   = (const int*)d_in[1];
    const float* emb   = (const float*)d_in[2];
    const float* Wih0f = (const float*)d_in[3];
    const float* Whh0f = (const float*)d_in[4];
    const float* b0f   = (const float*)d_in[5];
    const float* Wih0b = (const float*)d_in[6];
    const float* Whh0b = (const float*)d_in[7];
    const float* b0b   = (const float*)d_in[8];
    const float* Wih1f = (const float*)d_in[9];
    const float* Whh1f = (const float*)d_in[10];
    const float* b1f   = (const float*)d_in[11];
    const float* Wih1b = (const float*)d_in[12];
    const float* Whh1b = (const float*)d_in[13];
    const float* b1b   = (const float*)d_in[14];
    const float* Wsbj  = (const float*)d_in[15];
    const float* bsbj  = (const float*)d_in[16];
    const float* start_t = (const float*)d_in[17];
    const float* end_t   = (const float*)d_in[18];
    const float* trans   = (const float*)d_in[19];

    // workspace map (bytes), max ~102.84 MB. Overlaps (stream-ordered lifetimes):
    //   Wb0f/Wb0b in h0 region (dead before lstm0 writes h0)
    //   Abf, Wb1f/Wb1b in h1 region (dead before lstm1 writes h1)
    //   em reuses zf (dead after lstm1)
    char* ws = (char*)d_ws;
    unsigned short* zf   = (unsigned short*)(ws + 0);           // 32 MiB
    unsigned short* zb   = (unsigned short*)(ws + 33554432);    // 32 MiB
    unsigned short* h0   = (unsigned short*)(ws + 67108864);    // 16 MiB
    unsigned short* h1   = (unsigned short*)(ws + 83886080);    // 16 MiB
    unsigned short* Wb0f = (unsigned short*)(ws + 67108864);    // 1024x320 bf16
    unsigned short* Wb0b = (unsigned short*)(ws + 67764224);
    unsigned short* Abf  = (unsigned short*)(ws + 83886080);    // 16384x320 bf16 (10 MiB)
    unsigned short* Wb1f = (unsigned short*)(ws + 94371840);    // 1024x512 bf16
    unsigned short* Wb1b = (unsigned short*)(ws + 95420416);
    unsigned int*   WQ   = (unsigned int*)(ws + 100663296);     // 4 x 256 KiB int8 weights
    float*          Sq   = (float*)(ws + 101711872);            // 4 x 4 KiB scales
    unsigned short* WsbjB = (unsigned short*)(ws + 102760448);  // 64x512 bf16 (64 KiB)
    float*          acc  = (float*)(ws + 102836224);            // 8 B
    float*           em  = (float*)(ws + 0);                    // 2.4 MiB (over zf)
    float* out = (float*)d_out;

    const int* WQ0f = (const int*)(WQ + 0 * 65536);
    const int* WQ0b = (const int*)(WQ + 1 * 65536);
    const int* WQ1f = (const int*)(WQ + 2 * 65536);
    const int* WQ1b = (const int*)(WQ + 3 * 65536);
    const float* S0f = Sq + 0 * 1024;
    const float* S0b = Sq + 1 * 1024;
    const float* S1f = Sq + 2 * 1024;
    const float* S1b = Sq + 3 * 1024;

    init_kernel<<<1, 64, 0, stream>>>(acc);
    conv_scale<<<dim3(4096), 64, 0, stream>>>(Whh0f, Whh0b, Whh1f, Whh1b, Sq);
    conv_wq<<<dim3(1024), 256, 0, stream>>>(Whh0f, Whh0b, Whh1f, Whh1b, Sq, WQ);
    conv_wsbj_bf<<<dim3(128), 256, 0, stream>>>(Wsbj, WsbjB);
    conv_gather<<<dim3(MTOT), 320, 0, stream>>>(text, emb, Abf);
    conv_w4<<<dim3(2048, 4), 256, 0, stream>>>(Wih0f, Wih0b, Wih1f, Wih1b,
                                               Wb0f, Wb0b, Wb1f, Wb1b);

    // layer 0 input projection (MFMA), f+b in one dispatch
    gemm_mfma2<<<dim3(128, 8, 2), 256, 0, stream>>>(Abf, Wb0f, Wb0b, b0f, b0b, zf, zb, KP0);
    lstm_kernel<<<dim3(BB, 2), 1024, 0, stream>>>(zf, zb, WQ0f, WQ0b, S0f, S0b, h0);
    // layer 1 input projection (MFMA), f+b in one dispatch
    gemm_mfma2<<<dim3(128, 8, 2), 256, 0, stream>>>(h0, Wb1f, Wb1b, b1f, b1b, zf, zb, 512);
    lstm_kernel<<<dim3(BB, 2), 1024, 0, stream>>>(zf, zb, WQ1f, WQ1b, S1f, S1b, h1);

    gemm_em<<<dim3(128), 256, 0, stream>>>(h1, WsbjB, bsbj, em);
    crf_kernel<<<BB, 64, 0, stream>>>(text, sbj, em, start_t, end_t, trans, acc);
    final_kernel<<<1, 1, 0, stream>>>(acc, out);
}